// Round 14
// baseline (293.717 us; speedup 1.0000x reference)
//
#include <hip/hip_runtime.h>
#include <stdint.h>
#include <stddef.h>

#define BATCH 2
#define NELEM 131072           // anchors per batch (2^17)
#define OUT_NUM 2000
#define KCAP 32
#define PREWIN 16384
#define KPRE_W (PREWIN / 64)

__device__ __forceinline__ float exp32cr(float x) { return (float)exp((double)x); }

// Decision "IoU > 0.7" bit-equivalent to numpy-f32 fl(inter/den) > 0.7f (validated
// absmax=0 for 8 rounds): multiply-compare, exact __fdiv_rn inside guard band.
__device__ __forceinline__ bool iou_gt(float by1, float bx1, float by2, float bx2,
                                       float cy1, float cx1, float cy2, float cx2) {
    float y1 = fmaxf(by1, cy1), x1 = fmaxf(bx1, cx1);
    float y2 = fminf(by2, cy2), x2 = fminf(bx2, cx2);
    float ih = __fsub_rn(y2, y1), iw = __fsub_rn(x2, x1);
    if (ih <= 0.0f || iw <= 0.0f) return false;
    float inter = __fmul_rn(ih, iw);
    float a1 = __fmul_rn(__fsub_rn(by2, by1), __fsub_rn(bx2, bx1));
    float a2 = __fmul_rn(__fsub_rn(cy2, cy1), __fsub_rn(cx2, cx1));
    float den = __fadd_rn(__fsub_rn(__fadd_rn(a1, a2), inter), 1e-8f);
    float rhs = __fmul_rn(0.7f, den);
    if (inter > __fmul_rn(rhs, 1.0001f)) return true;
    if (inter < __fmul_rn(rhs, 0.9999f)) return false;
    return __fdiv_rn(inter, den) > 0.7f;
}
__device__ __forceinline__ bool iou_gt4(float4 a, float4 c) {
    return iou_gt(a.x, a.y, a.z, a.w, c.x, c.y, c.z, c.w);
}

// NECESSARY condition for IoU>0.7 (validated absmax=0, rounds 6-13)
__device__ __forceinline__ bool maybe4(float4 A, float4 C) {
    float dy = fabsf((A.x + A.z) - (C.x + C.z));
    float dx = fabsf((A.y + A.w) - (C.y + C.w));
    float hs = (A.z - A.x) + (C.z - C.x);
    float ws = (A.w - A.y) + (C.w - C.y);
    return (dy < 0.19f * hs) && (dx < 0.19f * ws);
}

// f32 box decode mirroring numpy-f32 (no contraction, CR exp)
__device__ __forceinline__ void decode_f(const float* __restrict__ deltas,
                                         const float* __restrict__ anchors,
                                         size_t gi, float* bx) {
    float a0 = anchors[4 * gi], a1 = anchors[4 * gi + 1];
    float a2 = anchors[4 * gi + 2], a3 = anchors[4 * gi + 3];
    float h = __fsub_rn(a2, a0), w = __fsub_rn(a3, a1);
    float cy = __fmul_rn(__fadd_rn(a2, a0), 0.5f);
    float cx = __fmul_rn(__fadd_rn(a3, a1), 0.5f);
    float d0 = __fmul_rn(deltas[4 * gi], 0.1f);
    float d1 = __fmul_rn(deltas[4 * gi + 1], 0.1f);
    float d2 = __fmul_rn(deltas[4 * gi + 2], 0.2f);
    float d3 = __fmul_rn(deltas[4 * gi + 3], 0.2f);
    cy = __fadd_rn(cy, __fmul_rn(d0, h));
    cx = __fadd_rn(cx, __fmul_rn(d1, w));
    h = __fmul_rn(h, exp32cr(d2));
    w = __fmul_rn(w, exp32cr(d3));
    bx[0] = __fsub_rn(cy, __fmul_rn(h, 0.5f));
    bx[1] = __fsub_rn(cx, __fmul_rn(w, 0.5f));
    bx[2] = __fadd_rn(cy, __fmul_rn(h, 0.5f));
    bx[3] = __fadd_rn(cx, __fmul_rn(w, 0.5f));
}

__device__ __forceinline__ float score_f(const float* __restrict__ logits, size_t gi) {
    float l0 = logits[2 * gi], l1 = logits[2 * gi + 1];
    float m = fmaxf(l0, l1);
    float e0 = exp32cr(__fsub_rn(l0, m));
    float e1 = exp32cr(__fsub_rn(l1, m));
    return __fdiv_rn(e1, __fadd_rn(e0, e1));
}

// key = f32-score-bits << 17 | 17-bit ~idx ; zeroes flag + state
__global__ __launch_bounds__(256) void prep_kernel(
    const float* __restrict__ logits, uint64_t* __restrict__ keys,
    uint32_t* __restrict__ flag, uint32_t* __restrict__ state) {
    int i = blockIdx.x * 256 + threadIdx.x;
    if (i == 0) *flag = 0;
    if (i < 32) state[i] = 0;
    if (i >= BATCH * NELEM) return;
    float s = score_f(logits, (size_t)i);
    uint32_t idx = (uint32_t)(i & (NELEM - 1));
    uint64_t key = 0;
    if (s > 0.05f)
        key = ((uint64_t)__float_as_uint(s) << 17) | ((~idx) & 0x1FFFFu);
    keys[i] = key;
}

// ---- bitonic sort (descending per batch) ------------------------------------
__global__ __launch_bounds__(1024) void bitonic_local_sort4(uint64_t* __restrict__ keys) {
    __shared__ uint64_t sh[4096];
    const int t = threadIdx.x;
    const size_t base = (size_t)blockIdx.x * 4096;
    for (int e = t; e < 4096; e += 1024) sh[e] = keys[base + e];
    __syncthreads();
    const int gb = (int)(base & (NELEM - 1));
    for (int k = 2; k <= 4096; k <<= 1) {
        for (int j = k >> 1; j >= 1; j >>= 1) {
            for (int pp = t; pp < 2048; pp += 1024) {
                int a = ((pp & ~(j - 1)) << 1) | (pp & (j - 1));
                bool ddd = (((gb + a) & k) == 0);
                uint64_t x = sh[a], y = sh[a + j];
                bool sw = ddd ? (x < y) : (x > y);
                if (sw) { sh[a] = y; sh[a + j] = x; }
            }
            __syncthreads();
        }
    }
    for (int e = t; e < 4096; e += 1024) keys[base + e] = sh[e];
}

__global__ __launch_bounds__(256) void bitonic_global_pass(uint64_t* __restrict__ keys,
                                                           int k, int j) {
    int tid = blockIdx.x * blockDim.x + threadIdx.x;
    const int half = NELEM / 2;
    int b = tid / half;
    int tt = tid - b * half;
    int a = ((tt & ~(j - 1)) << 1) | (tt & (j - 1));
    uint64_t* kb = keys + (size_t)b * NELEM;
    bool ddd = ((a & k) == 0);
    uint64_t x = kb[a], y = kb[a + j];
    bool sw = ddd ? (x < y) : (x > y);
    if (sw) { kb[a] = y; kb[a + j] = x; }
}

__global__ __launch_bounds__(256) void bitonic_global_fused2(uint64_t* __restrict__ keys,
                                                             int k, int j) {
    int tid = blockIdx.x * 256 + threadIdx.x;
    const int q = NELEM / 4;
    int b = tid / q;
    int tt = tid - b * q;
    int jh = j >> 1;
    int x = ((tt & ~(jh - 1)) << 2) | (tt & (jh - 1));
    uint64_t* kb = keys + (size_t)b * NELEM;
    bool ddd = ((x & k) == 0);
    uint64_t e0 = kb[x], e1 = kb[x + jh], e2 = kb[x + j], e3 = kb[x + j + jh];
    uint64_t tmp;
#define CMPEX(A, B) { bool sw = ddd ? (A < B) : (A > B); if (sw) { tmp = A; A = B; B = tmp; } }
    CMPEX(e0, e2) CMPEX(e1, e3)
    CMPEX(e0, e1) CMPEX(e2, e3)
#undef CMPEX
    kb[x] = e0; kb[x + jh] = e1; kb[x + j] = e2; kb[x + j + jh] = e3;
}

// 3 fused levels (j, j/2, j/4) via 8-element gather at stride jq=j/4.
// Direction uniform: gathered offsets i*jq never carry into bit k.
__global__ __launch_bounds__(256) void bitonic_global_fused3(uint64_t* __restrict__ keys,
                                                             int k, int j) {
    int tid = blockIdx.x * 256 + threadIdx.x;
    const int q = NELEM / 8;
    int b = tid / q;
    int tt = tid - b * q;
    int jq = j >> 2;
    int x = ((tt & ~(jq - 1)) << 3) | (tt & (jq - 1));
    uint64_t* kb = keys + (size_t)b * NELEM;
    bool ddd = ((x & k) == 0);
    uint64_t e0 = kb[x], e1 = kb[x + jq], e2 = kb[x + 2 * jq], e3 = kb[x + 3 * jq];
    uint64_t e4 = kb[x + 4 * jq], e5 = kb[x + 5 * jq], e6 = kb[x + 6 * jq], e7 = kb[x + 7 * jq];
    uint64_t tmp;
#define CMPEX(A, B) { bool sw = ddd ? (A < B) : (A > B); if (sw) { tmp = A; A = B; B = tmp; } }
    CMPEX(e0, e4) CMPEX(e1, e5) CMPEX(e2, e6) CMPEX(e3, e7)   // stride 4 = j
    CMPEX(e0, e2) CMPEX(e1, e3) CMPEX(e4, e6) CMPEX(e5, e7)   // stride 2 = j/2
    CMPEX(e0, e1) CMPEX(e2, e3) CMPEX(e4, e5) CMPEX(e6, e7)   // stride 1 = j/4
#undef CMPEX
    kb[x] = e0; kb[x + jq] = e1; kb[x + 2 * jq] = e2; kb[x + 3 * jq] = e3;
    kb[x + 4 * jq] = e4; kb[x + 5 * jq] = e5; kb[x + 6 * jq] = e6; kb[x + 7 * jq] = e7;
}

// 4 fused levels (j, j/2, j/4, j/8) via 16-element gather at stride jq=j/8.
__global__ __launch_bounds__(256) void bitonic_global_fused4(uint64_t* __restrict__ keys,
                                                             int k, int j) {
    int tid = blockIdx.x * 256 + threadIdx.x;
    const int q = NELEM / 16;
    int b = tid / q;
    int tt = tid - b * q;
    int jq = j >> 3;
    int x = ((tt & ~(jq - 1)) << 4) | (tt & (jq - 1));
    uint64_t* kb = keys + (size_t)b * NELEM;
    bool ddd = ((x & k) == 0);
    uint64_t e[16];
#pragma unroll
    for (int i = 0; i < 16; ++i) e[i] = kb[x + i * jq];
    uint64_t tmp;
#define CMPEX(A, B) { bool sw = ddd ? (e[A] < e[B]) : (e[A] > e[B]); \
    if (sw) { tmp = e[A]; e[A] = e[B]; e[B] = tmp; } }
#pragma unroll
    for (int i = 0; i < 8; ++i) CMPEX(i, i + 8)               // stride 8 = j
#pragma unroll
    for (int g2 = 0; g2 < 16; g2 += 8) {
        CMPEX(g2 + 0, g2 + 4) CMPEX(g2 + 1, g2 + 5) CMPEX(g2 + 2, g2 + 6) CMPEX(g2 + 3, g2 + 7)
    }
#pragma unroll
    for (int g2 = 0; g2 < 16; g2 += 4) { CMPEX(g2 + 0, g2 + 2) CMPEX(g2 + 1, g2 + 3) }
#pragma unroll
    for (int g2 = 0; g2 < 16; g2 += 2) CMPEX(g2, g2 + 1)
#undef CMPEX
#pragma unroll
    for (int i = 0; i < 16; ++i) kb[x + i * jq] = e[i];
}

__global__ __launch_bounds__(1024) void bitonic_local_merge8(uint64_t* __restrict__ keys,
                                                             int k) {
    __shared__ uint64_t sh[8192];
    const int t = threadIdx.x;
    const size_t base = (size_t)blockIdx.x * 8192;
    for (int e = t; e < 8192; e += 1024) sh[e] = keys[base + e];
    __syncthreads();
    const bool ddd = (((int)(base & (NELEM - 1)) & k) == 0);
    for (int j = 4096; j >= 1; j >>= 1) {
        for (int pp = t; pp < 4096; pp += 1024) {
            int a = ((pp & ~(j - 1)) << 1) | (pp & (j - 1));
            uint64_t x = sh[a], y = sh[a + j];
            bool sw = ddd ? (x < y) : (x > y);
            if (sw) { sh[a] = y; sh[a + j] = x; }
        }
        __syncthreads();
    }
    for (int e = t; e < 8192; e += 1024) keys[base + e] = sh[e];
}

__global__ __launch_bounds__(256) void sort_check(const uint64_t* __restrict__ keys,
                                                  uint32_t* __restrict__ flag) {
    int i = blockIdx.x * 256 + threadIdx.x;
    if (i >= BATCH * NELEM) return;
    uint32_t q = (uint32_t)i & (NELEM - 1);
    if (q != NELEM - 1) {
        if (keys[i] < keys[i + 1]) atomicOr(flag, 1u);
    }
}

// ---- packed candidate records for top-M; zero kcount ------------------------
__global__ __launch_bounds__(256) void records_kernel(
    const uint64_t* __restrict__ keys, const float* __restrict__ deltas,
    const float* __restrict__ anchors, const float* __restrict__ logits,
    float* __restrict__ records, uint32_t* __restrict__ kcount, int M) {
    int g = blockIdx.x * 256 + threadIdx.x;
    if (g >= BATCH * M) return;
    kcount[g] = 0;
    int b = g / M, r = g - b * M;
    uint64_t key = keys[(size_t)b * NELEM + r];
    float4 r0, r1;
    if (key != 0) {
        uint32_t idx = (uint32_t)((~key) & 0x1FFFFu);
        size_t gi = (size_t)b * NELEM + idx;
        float bx[4];
        decode_f(deltas, anchors, gi, bx);
        r0 = make_float4(bx[0], bx[1], bx[2], bx[3]);
        r1 = make_float4(score_f(logits, gi), logits[2 * gi], logits[2 * gi + 1], 1.0f);
    } else {
        r0 = make_float4(0.f, 0.f, 0.f, 0.f);
        r1 = make_float4(0.f, 0.f, 0.f, 0.f);
    }
    float4* rp = (float4*)records;
    rp[(size_t)g * 2] = r0;
    rp[(size_t)g * 2 + 1] = r1;
}

// ---- kill masks: dense rows (overflow fallback) + sparse killer lists -------
__global__ __launch_bounds__(64) void mask_kernel(const float* __restrict__ records,
                                                  uint64_t* __restrict__ masks,
                                                  uint32_t* __restrict__ kcount,
                                                  uint16_t* __restrict__ klist, int M) {
    int ti = blockIdx.x, tj = blockIdx.y, b = blockIdx.z;
    if (tj > ti) return;
    int t = threadIdx.x;
    __shared__ float4 jb[64];
    __shared__ int jv[64];
    const float4* rp = (const float4*)records;
    {
        float4 rj  = rp[((size_t)b * M + (size_t)tj * 64 + t) * 2];
        float4 rj1 = rp[((size_t)b * M + (size_t)tj * 64 + t) * 2 + 1];
        jb[t] = rj;
        jv[t] = (rj1.w != 0.f);
    }
    const int i = ti * 64 + t;
    float4 ri  = rp[((size_t)b * M + i) * 2];
    float4 ri1 = rp[((size_t)b * M + i) * 2 + 1];
    bool iv = (ri1.w != 0.f);
    __syncthreads();
    uint64_t word = 0;
    if (iv) {
        for (int jj = 0; jj < 64; ++jj) {
            bool earlier = (tj < ti) || (jj < t);
            if (earlier && jv[jj] && maybe4(jb[jj], ri) && iou_gt4(jb[jj], ri)) {
                word |= 1ull << jj;
                uint32_t slot = atomicAdd(&kcount[(size_t)b * M + i], 1u);
                if (slot < KCAP)
                    klist[((size_t)b * M + i) * KCAP + slot] = (uint16_t)(tj * 64 + jj);
            }
        }
    }
    masks[((size_t)b * M + i) * (size_t)(M >> 6) + tj] = word;
}

// ---- G1: sparse-list greedy walk, CHUNK=256, bulk-accept scan ---------------
__global__ void nms_walk(
    const float* __restrict__ records, const uint64_t* __restrict__ masks,
    const uint32_t* __restrict__ kcount, const uint16_t* __restrict__ klist,
    float4* __restrict__ accbox, uint32_t* __restrict__ state,
    float* __restrict__ out, int M) {
    const int b = blockIdx.x;
    const int t = threadIdx.x;
    const int Wm = M >> 6;
    const int NC = M >> 8;
    const uint64_t* mb = masks + (size_t)b * M * (size_t)Wm;
    const float4* rp = (const float4*)records + (size_t)b * M * 2;

    __shared__ uint64_t accset[128];
    __shared__ uint64_t bwLDS[256][4];
    __shared__ uint8_t kf[256];
    __shared__ float4 recLDS[512];
    __shared__ uint32_t s_state[16];

    for (int w = t; w < 128; w += blockDim.x) accset[w] = 0;
    __syncthreads();

    int n_acc = 0, done = 0;
    for (int ci = 0; ci < NC && !done; ++ci) {
        const int p = ci << 8;
        const int pw = ci << 2;
        if (t < 256) {
            const int gi = p + t;
            uint32_t cnt = kcount[(size_t)b * M + gi];
            uint64_t rq0 = 0, rq1 = 0, rq2 = 0, rq3 = 0;
            bool kill = false;
            if (cnt <= KCAP) {
                const uint16_t* lp = klist + ((size_t)b * M + gi) * KCAP;
                for (uint32_t u = 0; u < cnt; ++u) {
                    int j = lp[u];
                    if (j < p) {
                        if ((accset[j >> 6] >> (j & 63)) & 1) kill = true;
                    } else {
                        int d = j - p;
                        uint64_t bit = 1ull << (d & 63);
                        switch (d >> 6) {
                            case 0: rq0 |= bit; break;
                            case 1: rq1 |= bit; break;
                            case 2: rq2 |= bit; break;
                            default: rq3 |= bit; break;
                        }
                    }
                }
            } else {
                const uint64_t* row = mb + (size_t)gi * Wm;
                uint64_t o = 0;
                for (int w = 0; w < pw; ++w) o |= row[w] & accset[w];
                kill = (o != 0);
                rq0 = row[pw]; rq1 = row[pw + 1];
                rq2 = row[pw + 2]; rq3 = row[pw + 3];
            }
            kf[t] = kill ? 1 : 0;
            bwLDS[t][0] = rq0; bwLDS[t][1] = rq1;
            bwLDS[t][2] = rq2; bwLDS[t][3] = rq3;
        } else if (t < 512) {
            int i0 = t - 256;
            recLDS[i0] = rp[(size_t)p * 2 + i0];
            recLDS[i0 + 256] = rp[(size_t)p * 2 + i0 + 256];
        }
        __syncthreads();

        // D: wave 0 — bulk accept + short serial resolution of conflicted rows
        if (t < 64) {
            const int l = t;
            uint64_t b00 = bwLDS[l][0], b01 = bwLDS[l][1], b02 = bwLDS[l][2], b03 = bwLDS[l][3];
            uint64_t b10 = bwLDS[64 + l][0], b11 = bwLDS[64 + l][1], b12 = bwLDS[64 + l][2], b13 = bwLDS[64 + l][3];
            uint64_t b20 = bwLDS[128 + l][0], b21 = bwLDS[128 + l][1], b22 = bwLDS[128 + l][2], b23 = bwLDS[128 + l][3];
            uint64_t b30 = bwLDS[192 + l][0], b31 = bwLDS[192 + l][1], b32 = bwLDS[192 + l][2], b33 = bwLDS[192 + l][3];
            uint64_t vm0 = __ballot(recLDS[2 * l + 1].w != 0.f);
            uint64_t vm1 = __ballot(recLDS[2 * (64 + l) + 1].w != 0.f);
            uint64_t vm2 = __ballot(recLDS[2 * (128 + l) + 1].w != 0.f);
            uint64_t vm3 = __ballot(recLDS[2 * (192 + l) + 1].w != 0.f);
            uint64_t k0 = __ballot(kf[l] != 0);
            uint64_t k1 = __ballot(kf[64 + l] != 0);
            uint64_t k2 = __ballot(kf[128 + l] != 0);
            uint64_t k3 = __ballot(kf[192 + l] != 0);
            uint64_t e0m = __ballot((b00 | b01 | b02 | b03) == 0);
            uint64_t e1m = __ballot((b10 | b11 | b12 | b13) == 0);
            uint64_t e2m = __ballot((b20 | b21 | b22 | b23) == 0);
            uint64_t e3m = __ballot((b30 | b31 | b32 | b33) == 0);
            if (t == 0) {
                uint64_t t0 = vm0 & ~k0, t1 = vm1 & ~k1, t2 = vm2 & ~k2, t3 = vm3 & ~k3;
                uint64_t a0 = t0 & e0m, a1 = t1 & e1m, a2 = t2 & e2m, a3 = t3 & e3m;
                uint64_t c0 = t0 & ~e0m, c1 = t1 & ~e1m, c2 = t2 & ~e2m, c3 = t3 & ~e3m;
#define RESOLVE(cq, aq, base) \
    while (cq) { int cb = __builtin_ctzll(cq); cq &= cq - 1; \
        int idx = (base) + cb; \
        uint64_t w0 = bwLDS[idx][0], w1 = bwLDS[idx][1]; \
        uint64_t w2 = bwLDS[idx][2], w3 = bwLDS[idx][3]; \
        if (!((w0 & a0) | (w1 & a1) | (w2 & a2) | (w3 & a3))) aq |= (1ull << cb); }
                RESOLVE(c0, a0, 0)
                RESOLVE(c1, a1, 64)
                RESOLVE(c2, a2, 128)
                RESOLVE(c3, a3, 192)
#undef RESOLVE
                int n = n_acc;
                int dn = ((vm0 & vm1 & vm2 & vm3) != ~0ull) ? 1 : 0;
                int tot = (int)(__popcll(a0) + __popcll(a1) + __popcll(a2) + __popcll(a3));
                int rem = OUT_NUM - n;
                if (tot >= rem) {   // exact keep-first-rem truncation
                    int keep = rem;
#define TRUNC(w) { int pc = (int)__popcll(w); \
    if (keep >= pc) keep -= pc; \
    else { while ((int)__popcll(w) > keep) w &= ~(1ull << (63 - __builtin_clzll(w))); keep = 0; } }
                    TRUNC(a0) TRUNC(a1) TRUNC(a2) TRUNC(a3)
#undef TRUNC
                    n = OUT_NUM; dn = 1;
                } else {
                    n += tot;
                }
                s_state[0] = (uint32_t)n_acc;
                s_state[1] = (uint32_t)n;
                s_state[2] = (uint32_t)dn;
                s_state[3] = (uint32_t)a0; s_state[4] = (uint32_t)(a0 >> 32);
                s_state[5] = (uint32_t)a1; s_state[6] = (uint32_t)(a1 >> 32);
                s_state[7] = (uint32_t)a2; s_state[8] = (uint32_t)(a2 >> 32);
                s_state[9] = (uint32_t)a3; s_state[10] = (uint32_t)(a3 >> 32);
                accset[pw] = a0; accset[pw + 1] = a1;
                accset[pw + 2] = a2; accset[pw + 3] = a3;
            }
        }
        __syncthreads();
        int r0 = (int)s_state[0];
        n_acc = (int)s_state[1];
        done = (int)s_state[2];
        uint64_t amA = ((uint64_t)s_state[4] << 32) | s_state[3];
        uint64_t amB = ((uint64_t)s_state[6] << 32) | s_state[5];
        uint64_t amC = ((uint64_t)s_state[8] << 32) | s_state[7];
        uint64_t amD = ((uint64_t)s_state[10] << 32) | s_state[9];

        if (t < 256) {
            int q = t >> 6, ll = t & 63;
            uint64_t amq = q == 0 ? amA : q == 1 ? amB : q == 2 ? amC : amD;
            if ((amq >> ll) & 1) {
                int base = r0;
                if (q > 0) base += (int)__popcll(amA);
                if (q > 1) base += (int)__popcll(amB);
                if (q > 2) base += (int)__popcll(amC);
                int row = base + (int)__popcll(amq & ((1ull << ll) - 1ull));
                float4 cb = recLDS[t * 2], cm = recLDS[t * 2 + 1];
                accbox[(size_t)b * OUT_NUM + row] = cb;
                float* ob = out + ((size_t)b * OUT_NUM + row) * 5;
                ob[0] = cb.x; ob[1] = cb.y; ob[2] = cb.z; ob[3] = cb.w; ob[4] = 1.0f;
                float* os = out + (size_t)BATCH * OUT_NUM * 5 +
                            ((size_t)b * OUT_NUM + row) * 2;
                os[0] = cm.x; os[1] = 1.0f;
                float* ol = out + (size_t)BATCH * OUT_NUM * 7 +
                            ((size_t)b * OUT_NUM + row) * 3;
                ol[0] = cm.y; ol[1] = cm.z; ol[2] = 1.0f;
            }
        }
        __syncthreads();
    }
    if (t == 0) {
        state[b * 16] = (uint32_t)n_acc;
        state[b * 16 + 1] = (uint32_t)done;
    }
}

// ---- prekill v3: aF-only LDS, 1024 threads, cooperative early-exit ----------
__global__ __launch_bounds__(1024) void prekill_kernel(
    const uint64_t* __restrict__ keys, const float* __restrict__ deltas,
    const float* __restrict__ anchors, const float4* __restrict__ accbox,
    const uint32_t* __restrict__ state, uint64_t* __restrict__ kpre, int Mend) {
    const int blk = blockIdx.x, b = blockIdx.y;
    const int t = threadIdx.x;
    const int c = t & 63, g = t >> 6;   // 16 threads per candidate
    const int n1 = (int)state[b * 16];
    __shared__ float4 aF[OUT_NUM];      // 32 KB
    __shared__ float4 jb[64];
    __shared__ uint8_t kfl[64];
    for (int r = t; r < n1; r += 1024) aF[r] = accbox[(size_t)b * OUT_NUM + r];
    if (t < 64) {
        kfl[t] = 0;
        int j = Mend + blk * 64 + t;
        uint64_t key = keys[(size_t)b * NELEM + j];
        float4 bx4 = make_float4(0.f, 0.f, 0.f, 0.f);
        if (key != 0) {
            uint32_t idx = (uint32_t)((~key) & 0x1FFFFu);
            size_t gi = (size_t)b * NELEM + idx;
            float bx[4];
            decode_f(deltas, anchors, gi, bx);
            bx4 = make_float4(bx[0], bx[1], bx[2], bx[3]);
        }
        jb[t] = bx4;
    }
    __syncthreads();
    volatile uint8_t* vk = kfl;         // monotonic flag; stale 0 = extra work only
    float4 cb = jb[c];
    float csy = cb.x + cb.z, csx = cb.y + cb.w;
    float ch19 = 0.19f * (cb.z - cb.x), cw19 = 0.19f * (cb.w - cb.y);
    bool k = false;
    for (int a = g; a < n1; a += 16) {
        if (vk[c]) break;               // another thread already killed it
        float4 af = aF[a];
        float asy = af.x + af.z, asx = af.y + af.w;
        float ah19 = 0.19f * (af.z - af.x), aw19 = 0.19f * (af.w - af.y);
        if (fabsf(asy - csy) < ah19 + ch19 && fabsf(asx - csx) < aw19 + cw19) {
            if (iou_gt4(af, cb)) { k = true; break; }
        }
    }
    if (k) kfl[c] = 1;   // benign same-value race
    __syncthreads();
    if (t < 64) {
        uint64_t w = __ballot(kfl[t] != 0);
        if (t == 0) kpre[(size_t)b * KPRE_W + blk] = w;
    }
}

// ---- G2: tail beyond M, CHUNK=256, prekill window + full-scan fallback ------
__global__ __launch_bounds__(512) void nms_tail(
    const uint64_t* __restrict__ keys, const float* __restrict__ deltas,
    const float* __restrict__ logits, const float* __restrict__ anchors,
    const float4* __restrict__ accbox, const uint32_t* __restrict__ state,
    const uint64_t* __restrict__ kpre, float* __restrict__ out,
    int Mend, int hasPre) {
    const int b = blockIdx.x;
    const int t = threadIdx.x;
    const int l = t & 63;

    __shared__ float4 aF4[OUT_NUM];
    __shared__ float4 aS4[OUT_NUM];
    __shared__ float4 cbox[256], cmeta[256];
    __shared__ uint32_t transW[256][8];
    __shared__ uint8_t kf2[512];
    __shared__ uint64_t kpreLDS[4];
    __shared__ uint32_t s_state[16];

    if (t == 0) {
        s_state[0] = state[b * 16];
        s_state[1] = state[b * 16 + 1];
    }
    __syncthreads();
    int n_acc = (int)s_state[0];
    int done = (int)s_state[1];
    const int tailStart = n_acc;
    for (int r = t; r < n_acc; r += 512) {
        float4 ab = accbox[(size_t)b * OUT_NUM + r];
        aF4[r] = ab;
        aS4[r] = make_float4(ab.x + ab.z, ab.y + ab.w, ab.z - ab.x, ab.w - ab.y);
    }
    __syncthreads();

    for (int p = Mend; p < NELEM && !done; p += 256) {
        const bool inwin = hasPre && (p < Mend + PREWIN);
        for (int i = t; i < 2048; i += 512) ((uint32_t*)transW)[i] = 0;
        if (t < 256) {
            uint64_t key = keys[(size_t)b * NELEM + p + t];
            float4 bx4 = make_float4(0.f, 0.f, 0.f, 0.f);
            float4 mt = make_float4(0.f, 0.f, 0.f, 0.f);
            if (key != 0) {
                uint32_t idx = (uint32_t)((~key) & 0x1FFFFu);
                size_t gi = (size_t)b * NELEM + idx;
                float bx[4];
                decode_f(deltas, anchors, gi, bx);
                bx4 = make_float4(bx[0], bx[1], bx[2], bx[3]);
                mt = make_float4(score_f(logits, gi), logits[2 * gi],
                                 logits[2 * gi + 1], 1.0f);
            }
            cbox[t] = bx4; cmeta[t] = mt;
        }
        if (t < 4)
            kpreLDS[t] = inwin ? kpre[(size_t)b * KPRE_W + ((p - Mend) >> 6) + t] : 0ull;
        __syncthreads();

        // B: killed-by-accepted (within window: only tail-born accepts)
        {
            const int c = t & 255, g = t >> 8;
            float4 cb = cbox[c];
            bool pkc = inwin && ((kpreLDS[c >> 6] >> (c & 63)) & 1);
            bool valid = (cmeta[c].w != 0.f) && !pkc;
            float csy = cb.x + cb.z, csx = cb.y + cb.w;
            float chh = cb.z - cb.x, cww = cb.w - cb.y;
            bool k = false;
            int aStart = inwin ? tailStart : 0;
            if (valid) {
                for (int a = aStart + g; a < n_acc; a += 2) {
                    float4 as = aS4[a];
                    if (fabsf(as.x - csy) < 0.19f * (as.z + chh) &&
                        fabsf(as.y - csx) < 0.19f * (as.w + cww)) {
                        if (iou_gt4(aF4[a], cb)) { k = true; break; }
                    }
                }
            }
            kf2[t] = k ? 1 : 0;
        }
        __syncthreads();   // C sees B's kills, skips dead pairs

        // C: intra-chunk killers among survivors only
        for (int pid = t; pid < 256 * 256; pid += 512) {
            int c0 = pid >> 8, c1 = pid & 255;
            if (c1 > c0 && cmeta[c0].w != 0.f && cmeta[c1].w != 0.f) {
                bool d0 = (inwin && ((kpreLDS[c0 >> 6] >> (c0 & 63)) & 1)) ||
                          kf2[c0] || kf2[256 + c0];
                bool d1 = (inwin && ((kpreLDS[c1 >> 6] >> (c1 & 63)) & 1)) ||
                          kf2[c1] || kf2[256 + c1];
                if (!d0 && !d1 && maybe4(cbox[c0], cbox[c1]) &&
                    iou_gt4(cbox[c0], cbox[c1]))
                    atomicOr(&transW[c1][c0 >> 5], 1u << (c0 & 31));
            }
        }
        __syncthreads();

        // D: wave0 scan
        if (t < 64) {
            uint64_t bw00, bw01, bw02, bw03, bw10, bw11, bw12, bw13;
            uint64_t bw20, bw21, bw22, bw23, bw30, bw31, bw32, bw33;
            bw00 = ((uint64_t)transW[l][1] << 32) | transW[l][0];
            bw01 = ((uint64_t)transW[l][3] << 32) | transW[l][2];
            bw02 = ((uint64_t)transW[l][5] << 32) | transW[l][4];
            bw03 = ((uint64_t)transW[l][7] << 32) | transW[l][6];
            bw10 = ((uint64_t)transW[64 + l][1] << 32) | transW[64 + l][0];
            bw11 = ((uint64_t)transW[64 + l][3] << 32) | transW[64 + l][2];
            bw12 = ((uint64_t)transW[64 + l][5] << 32) | transW[64 + l][4];
            bw13 = ((uint64_t)transW[64 + l][7] << 32) | transW[64 + l][6];
            bw20 = ((uint64_t)transW[128 + l][1] << 32) | transW[128 + l][0];
            bw21 = ((uint64_t)transW[128 + l][3] << 32) | transW[128 + l][2];
            bw22 = ((uint64_t)transW[128 + l][5] << 32) | transW[128 + l][4];
            bw23 = ((uint64_t)transW[128 + l][7] << 32) | transW[128 + l][6];
            bw30 = ((uint64_t)transW[192 + l][1] << 32) | transW[192 + l][0];
            bw31 = ((uint64_t)transW[192 + l][3] << 32) | transW[192 + l][2];
            bw32 = ((uint64_t)transW[192 + l][5] << 32) | transW[192 + l][4];
            bw33 = ((uint64_t)transW[192 + l][7] << 32) | transW[192 + l][6];
            uint64_t vm0 = __ballot(cmeta[l].w != 0.f);
            uint64_t vm1 = __ballot(cmeta[64 + l].w != 0.f);
            uint64_t vm2 = __ballot(cmeta[128 + l].w != 0.f);
            uint64_t vm3 = __ballot(cmeta[192 + l].w != 0.f);
            uint64_t k0 = kpreLDS[0] | __ballot((kf2[l] | kf2[256 + l]) != 0);
            uint64_t k1 = kpreLDS[1] | __ballot((kf2[64 + l] | kf2[320 + l]) != 0);
            uint64_t k2 = kpreLDS[2] | __ballot((kf2[128 + l] | kf2[384 + l]) != 0);
            uint64_t k3 = kpreLDS[3] | __ballot((kf2[192 + l] | kf2[448 + l]) != 0);
            uint64_t t0 = vm0 & ~k0, t1 = vm1 & ~k1, t2 = vm2 & ~k2, t3 = vm3 & ~k3;
            uint64_t am0 = 0, am1 = 0, am2 = 0, am3 = 0;
            int n = n_acc;
            int dn = ((vm0 & vm1 & vm2 & vm3) != ~0ull);
            while (t0 | t1 | t2 | t3) {
                int qb; uint64_t w;
                if (t0)      { qb = 0; w = t0; }
                else if (t1) { qb = 1; w = t1; }
                else if (t2) { qb = 2; w = t2; }
                else         { qb = 3; w = t3; }
                int lb = __builtin_ctzll(w);
                uint64_t bit = 1ull << lb;
                if (qb == 0) { am0 |= bit; t0 &= ~bit; }
                else if (qb == 1) { am1 |= bit; t1 &= ~bit; }
                else if (qb == 2) { am2 |= bit; t2 &= ~bit; }
                else { am3 |= bit; t3 &= ~bit; }
                ++n;
                if (n == OUT_NUM) { dn = 1; break; }
                uint64_t s0 = qb == 0 ? bw00 : qb == 1 ? bw01 : qb == 2 ? bw02 : bw03;
                uint64_t s1 = qb == 0 ? bw10 : qb == 1 ? bw11 : qb == 2 ? bw12 : bw13;
                uint64_t s2 = qb == 0 ? bw20 : qb == 1 ? bw21 : qb == 2 ? bw22 : bw23;
                uint64_t s3 = qb == 0 ? bw30 : qb == 1 ? bw31 : qb == 2 ? bw32 : bw33;
                t0 &= ~__ballot(((s0 >> lb) & 1) != 0);
                t1 &= ~__ballot(((s1 >> lb) & 1) != 0);
                t2 &= ~__ballot(((s2 >> lb) & 1) != 0);
                t3 &= ~__ballot(((s3 >> lb) & 1) != 0);
            }
            if (t == 0) {
                s_state[0] = (uint32_t)n_acc;
                s_state[1] = (uint32_t)n;
                s_state[2] = (uint32_t)dn;
                s_state[3] = (uint32_t)am0; s_state[4] = (uint32_t)(am0 >> 32);
                s_state[5] = (uint32_t)am1; s_state[6] = (uint32_t)(am1 >> 32);
                s_state[7] = (uint32_t)am2; s_state[8] = (uint32_t)(am2 >> 32);
                s_state[9] = (uint32_t)am3; s_state[10] = (uint32_t)(am3 >> 32);
            }
        }
        __syncthreads();
        int r0 = (int)s_state[0];
        n_acc = (int)s_state[1];
        done = (int)s_state[2];
        uint64_t amA = ((uint64_t)s_state[4] << 32) | s_state[3];
        uint64_t amB = ((uint64_t)s_state[6] << 32) | s_state[5];
        uint64_t amC = ((uint64_t)s_state[8] << 32) | s_state[7];
        uint64_t amD = ((uint64_t)s_state[10] << 32) | s_state[9];

        if (t < 256) {
            int q = t >> 6, ll = t & 63;
            uint64_t amq = q == 0 ? amA : q == 1 ? amB : q == 2 ? amC : amD;
            if ((amq >> ll) & 1) {
                int base = r0;
                if (q > 0) base += (int)__popcll(amA);
                if (q > 1) base += (int)__popcll(amB);
                if (q > 2) base += (int)__popcll(amC);
                int row = base + (int)__popcll(amq & ((1ull << ll) - 1ull));
                float4 cb = cbox[t];
                float4 cm = cmeta[t];
                aF4[row] = cb;
                aS4[row] = make_float4(cb.x + cb.z, cb.y + cb.w,
                                       cb.z - cb.x, cb.w - cb.y);
                float* ob = out + ((size_t)b * OUT_NUM + row) * 5;
                ob[0] = cb.x; ob[1] = cb.y; ob[2] = cb.z; ob[3] = cb.w; ob[4] = 1.0f;
                float* os = out + (size_t)BATCH * OUT_NUM * 5 +
                            ((size_t)b * OUT_NUM + row) * 2;
                os[0] = cm.x; os[1] = 1.0f;
                float* ol = out + (size_t)BATCH * OUT_NUM * 7 +
                            ((size_t)b * OUT_NUM + row) * 3;
                ol[0] = cm.y; ol[1] = cm.z; ol[2] = 1.0f;
            }
        }
        __syncthreads();
    }

    for (int r = n_acc + t; r < OUT_NUM; r += 512) {
        float* ob = out + ((size_t)b * OUT_NUM + r) * 5;
        ob[0] = 0.f; ob[1] = 0.f; ob[2] = 0.f; ob[3] = 0.f; ob[4] = 0.f;
        float* os = out + (size_t)BATCH * OUT_NUM * 5 + ((size_t)b * OUT_NUM + r) * 2;
        os[0] = 0.f; os[1] = 0.f;
        float* ol = out + (size_t)BATCH * OUT_NUM * 7 + ((size_t)b * OUT_NUM + r) * 3;
        ol[0] = 0.f; ol[1] = 0.f; ol[2] = 0.f;
    }
    if (t == 0 && n_acc < OUT_NUM) out[0] = 2.0e5f;  // canary B
}

__global__ void canary_kernel(const uint32_t* __restrict__ flag, float* __restrict__ out,
                              int code) {
    if (code) { out[0] = 3.0e5f; return; }
    if (*flag) out[0] = 1.0e5f;
}

extern "C" void kernel_launch(void* const* d_in, const int* in_sizes, int n_in,
                              void* d_out, int out_size, void* d_ws, size_t ws_size,
                              hipStream_t stream) {
    const float* deltas  = (const float*)d_in[0];
    const float* logits  = (const float*)d_in[1];
    const float* anchors = (const float*)d_in[2];
    float* out = (float*)d_out;

    const size_t keysB = (size_t)BATCH * NELEM * 8;
    const size_t flagOff = keysB;
    const size_t stateOff = keysB + 256;
    const size_t kpreOff = keysB + 512;                       // 4 KB (PREWIN=16384)
    const size_t accOff = kpreOff + 8192;
    const size_t recOff = accOff + 65536;
    if (ws_size < recOff) {
        canary_kernel<<<1, 1, 0, stream>>>((const uint32_t*)d_ws, out, 1);
        return;
    }
    // tier select; walk block size encodes the tier for rocprof telemetry
    int M = 0, wbs = 512;
    const int tiers[3] = {8192, 4096, 2048};
    const int twbs[3]  = {512, 576, 640};
    for (int i = 0; i < 3; ++i) {
        int cand = tiers[i];
        size_t need = recOff + (size_t)BATCH * cand * 32 +
                      (size_t)BATCH * cand * (cand / 8) +
                      (size_t)BATCH * cand * 4 +
                      (size_t)BATCH * cand * KCAP * 2;
        if (ws_size >= need) { M = cand; wbs = twbs[i]; break; }
    }

    uint64_t* keys = (uint64_t*)d_ws;
    uint32_t* flag = (uint32_t*)((char*)d_ws + flagOff);
    uint32_t* state = (uint32_t*)((char*)d_ws + stateOff);
    uint64_t* kpre = (uint64_t*)((char*)d_ws + kpreOff);
    float4* accbox = (float4*)((char*)d_ws + accOff);
    float* records = (float*)((char*)d_ws + recOff);
    uint64_t* masks = (uint64_t*)((char*)d_ws + recOff + (size_t)BATCH * M * 32);
    uint32_t* kcount = (uint32_t*)((char*)masks + (size_t)BATCH * M * (M / 8));
    uint16_t* klist = (uint16_t*)((char*)kcount + (size_t)BATCH * M * 4);

    prep_kernel<<<(BATCH * NELEM) / 256, 256, 0, stream>>>(logits, keys, flag, state);

    bitonic_local_sort4<<<BATCH * NELEM / 4096, 1024, 0, stream>>>(keys);
    bitonic_local_merge8<<<BATCH * NELEM / 8192, 1024, 0, stream>>>(keys, 8192);
    bitonic_global_pass<<<(BATCH * NELEM / 2) / 256, 256, 0, stream>>>(keys, 16384, 8192);
    bitonic_local_merge8<<<BATCH * NELEM / 8192, 1024, 0, stream>>>(keys, 16384);
    bitonic_global_fused2<<<(BATCH * NELEM / 4) / 256, 256, 0, stream>>>(keys, 32768, 16384);
    bitonic_local_merge8<<<BATCH * NELEM / 8192, 1024, 0, stream>>>(keys, 32768);
    bitonic_global_fused3<<<(BATCH * NELEM / 8) / 256, 256, 0, stream>>>(keys, 65536, 32768);
    bitonic_local_merge8<<<BATCH * NELEM / 8192, 1024, 0, stream>>>(keys, 65536);
    bitonic_global_fused4<<<(BATCH * NELEM / 16) / 256, 256, 0, stream>>>(keys, 131072, 65536);
    bitonic_local_merge8<<<BATCH * NELEM / 8192, 1024, 0, stream>>>(keys, 131072);

    sort_check<<<(BATCH * NELEM) / 256, 256, 0, stream>>>(keys, flag);
    if (M > 0) {
        records_kernel<<<(BATCH * M) / 256, 256, 0, stream>>>(keys, deltas, anchors,
                                                              logits, records, kcount, M);
        dim3 mg(M / 64, M / 64, BATCH);
        mask_kernel<<<mg, 64, 0, stream>>>(records, masks, kcount, klist, M);
        nms_walk<<<BATCH, wbs, 0, stream>>>(records, masks, kcount, klist,
                                            accbox, state, out, M);
        dim3 pg(PREWIN / 64, BATCH);
        prekill_kernel<<<pg, 1024, 0, stream>>>(keys, deltas, anchors, accbox, state,
                                                kpre, M);
    }
    nms_tail<<<BATCH, 512, 0, stream>>>(keys, deltas, logits, anchors, accbox, state,
                                        kpre, out, M, (M > 0) ? 1 : 0);
    canary_kernel<<<1, 1, 0, stream>>>(flag, out, 0);
}

// Round 15
// 280.559 us; speedup vs baseline: 1.0469x; 1.0469x over previous
//
#include <hip/hip_runtime.h>
#include <stdint.h>
#include <stddef.h>

#define BATCH 2
#define NELEM 131072           // anchors per batch (2^17)
#define OUT_NUM 2000
#define KCAP 32
#define PREWIN 16384
#define KPRE_W (PREWIN / 64)

__device__ __forceinline__ float exp32cr(float x) { return (float)exp((double)x); }

// Decision "IoU > 0.7" bit-equivalent to numpy-f32 fl(inter/den) > 0.7f (validated
// absmax=0 for 9 rounds): multiply-compare, exact __fdiv_rn inside guard band.
__device__ __forceinline__ bool iou_gt(float by1, float bx1, float by2, float bx2,
                                       float cy1, float cx1, float cy2, float cx2) {
    float y1 = fmaxf(by1, cy1), x1 = fmaxf(bx1, cx1);
    float y2 = fminf(by2, cy2), x2 = fminf(bx2, cx2);
    float ih = __fsub_rn(y2, y1), iw = __fsub_rn(x2, x1);
    if (ih <= 0.0f || iw <= 0.0f) return false;
    float inter = __fmul_rn(ih, iw);
    float a1 = __fmul_rn(__fsub_rn(by2, by1), __fsub_rn(bx2, bx1));
    float a2 = __fmul_rn(__fsub_rn(cy2, cy1), __fsub_rn(cx2, cx1));
    float den = __fadd_rn(__fsub_rn(__fadd_rn(a1, a2), inter), 1e-8f);
    float rhs = __fmul_rn(0.7f, den);
    if (inter > __fmul_rn(rhs, 1.0001f)) return true;
    if (inter < __fmul_rn(rhs, 0.9999f)) return false;
    return __fdiv_rn(inter, den) > 0.7f;
}
__device__ __forceinline__ bool iou_gt4(float4 a, float4 c) {
    return iou_gt(a.x, a.y, a.z, a.w, c.x, c.y, c.z, c.w);
}

// NECESSARY condition for IoU>0.7 (validated absmax=0, rounds 6-14)
__device__ __forceinline__ bool maybe4(float4 A, float4 C) {
    float dy = fabsf((A.x + A.z) - (C.x + C.z));
    float dx = fabsf((A.y + A.w) - (C.y + C.w));
    float hs = (A.z - A.x) + (C.z - C.x);
    float ws = (A.w - A.y) + (C.w - C.y);
    return (dy < 0.19f * hs) && (dx < 0.19f * ws);
}

// f32 box decode mirroring numpy-f32 (no contraction, CR exp)
__device__ __forceinline__ void decode_f(const float* __restrict__ deltas,
                                         const float* __restrict__ anchors,
                                         size_t gi, float* bx) {
    float a0 = anchors[4 * gi], a1 = anchors[4 * gi + 1];
    float a2 = anchors[4 * gi + 2], a3 = anchors[4 * gi + 3];
    float h = __fsub_rn(a2, a0), w = __fsub_rn(a3, a1);
    float cy = __fmul_rn(__fadd_rn(a2, a0), 0.5f);
    float cx = __fmul_rn(__fadd_rn(a3, a1), 0.5f);
    float d0 = __fmul_rn(deltas[4 * gi], 0.1f);
    float d1 = __fmul_rn(deltas[4 * gi + 1], 0.1f);
    float d2 = __fmul_rn(deltas[4 * gi + 2], 0.2f);
    float d3 = __fmul_rn(deltas[4 * gi + 3], 0.2f);
    cy = __fadd_rn(cy, __fmul_rn(d0, h));
    cx = __fadd_rn(cx, __fmul_rn(d1, w));
    h = __fmul_rn(h, exp32cr(d2));
    w = __fmul_rn(w, exp32cr(d3));
    bx[0] = __fsub_rn(cy, __fmul_rn(h, 0.5f));
    bx[1] = __fsub_rn(cx, __fmul_rn(w, 0.5f));
    bx[2] = __fadd_rn(cy, __fmul_rn(h, 0.5f));
    bx[3] = __fadd_rn(cx, __fmul_rn(w, 0.5f));
}

__device__ __forceinline__ float score_f(const float* __restrict__ logits, size_t gi) {
    float l0 = logits[2 * gi], l1 = logits[2 * gi + 1];
    float m = fmaxf(l0, l1);
    float e0 = exp32cr(__fsub_rn(l0, m));
    float e1 = exp32cr(__fsub_rn(l1, m));
    return __fdiv_rn(e1, __fadd_rn(e0, e1));
}

// key = f32-score-bits << 17 | 17-bit ~idx ; zeroes flag + state
__global__ __launch_bounds__(256) void prep_kernel(
    const float* __restrict__ logits, uint64_t* __restrict__ keys,
    uint32_t* __restrict__ flag, uint32_t* __restrict__ state) {
    int i = blockIdx.x * 256 + threadIdx.x;
    if (i == 0) *flag = 0;
    if (i < 32) state[i] = 0;
    if (i >= BATCH * NELEM) return;
    float s = score_f(logits, (size_t)i);
    uint32_t idx = (uint32_t)(i & (NELEM - 1));
    uint64_t key = 0;
    if (s > 0.05f)
        key = ((uint64_t)__float_as_uint(s) << 17) | ((~idx) & 0x1FFFFu);
    keys[i] = key;
}

// ---- bitonic sort (descending per batch) ------------------------------------
__global__ __launch_bounds__(1024) void bitonic_local_sort4(uint64_t* __restrict__ keys) {
    __shared__ uint64_t sh[4096];
    const int t = threadIdx.x;
    const size_t base = (size_t)blockIdx.x * 4096;
    for (int e = t; e < 4096; e += 1024) sh[e] = keys[base + e];
    __syncthreads();
    const int gb = (int)(base & (NELEM - 1));
    for (int k = 2; k <= 4096; k <<= 1) {
        for (int j = k >> 1; j >= 1; j >>= 1) {
            for (int pp = t; pp < 2048; pp += 1024) {
                int a = ((pp & ~(j - 1)) << 1) | (pp & (j - 1));
                bool ddd = (((gb + a) & k) == 0);
                uint64_t x = sh[a], y = sh[a + j];
                bool sw = ddd ? (x < y) : (x > y);
                if (sw) { sh[a] = y; sh[a + j] = x; }
            }
            __syncthreads();
        }
    }
    for (int e = t; e < 4096; e += 1024) keys[base + e] = sh[e];
}

__global__ __launch_bounds__(256) void bitonic_global_pass(uint64_t* __restrict__ keys,
                                                           int k, int j) {
    int tid = blockIdx.x * blockDim.x + threadIdx.x;
    const int half = NELEM / 2;
    int b = tid / half;
    int tt = tid - b * half;
    int a = ((tt & ~(j - 1)) << 1) | (tt & (j - 1));
    uint64_t* kb = keys + (size_t)b * NELEM;
    bool ddd = ((a & k) == 0);
    uint64_t x = kb[a], y = kb[a + j];
    bool sw = ddd ? (x < y) : (x > y);
    if (sw) { kb[a] = y; kb[a + j] = x; }
}

__global__ __launch_bounds__(256) void bitonic_global_fused2(uint64_t* __restrict__ keys,
                                                             int k, int j) {
    int tid = blockIdx.x * 256 + threadIdx.x;
    const int q = NELEM / 4;
    int b = tid / q;
    int tt = tid - b * q;
    int jh = j >> 1;
    int x = ((tt & ~(jh - 1)) << 2) | (tt & (jh - 1));
    uint64_t* kb = keys + (size_t)b * NELEM;
    bool ddd = ((x & k) == 0);
    uint64_t e0 = kb[x], e1 = kb[x + jh], e2 = kb[x + j], e3 = kb[x + j + jh];
    uint64_t tmp;
#define CMPEX(A, B) { bool sw = ddd ? (A < B) : (A > B); if (sw) { tmp = A; A = B; B = tmp; } }
    CMPEX(e0, e2) CMPEX(e1, e3)
    CMPEX(e0, e1) CMPEX(e2, e3)
#undef CMPEX
    kb[x] = e0; kb[x + jh] = e1; kb[x + j] = e2; kb[x + j + jh] = e3;
}

// 3 fused levels (j, j/2, j/4) via 8-element gather at stride jq=j/4.
__global__ __launch_bounds__(256) void bitonic_global_fused3(uint64_t* __restrict__ keys,
                                                             int k, int j) {
    int tid = blockIdx.x * 256 + threadIdx.x;
    const int q = NELEM / 8;
    int b = tid / q;
    int tt = tid - b * q;
    int jq = j >> 2;
    int x = ((tt & ~(jq - 1)) << 3) | (tt & (jq - 1));
    uint64_t* kb = keys + (size_t)b * NELEM;
    bool ddd = ((x & k) == 0);
    uint64_t e0 = kb[x], e1 = kb[x + jq], e2 = kb[x + 2 * jq], e3 = kb[x + 3 * jq];
    uint64_t e4 = kb[x + 4 * jq], e5 = kb[x + 5 * jq], e6 = kb[x + 6 * jq], e7 = kb[x + 7 * jq];
    uint64_t tmp;
#define CMPEX(A, B) { bool sw = ddd ? (A < B) : (A > B); if (sw) { tmp = A; A = B; B = tmp; } }
    CMPEX(e0, e4) CMPEX(e1, e5) CMPEX(e2, e6) CMPEX(e3, e7)
    CMPEX(e0, e2) CMPEX(e1, e3) CMPEX(e4, e6) CMPEX(e5, e7)
    CMPEX(e0, e1) CMPEX(e2, e3) CMPEX(e4, e5) CMPEX(e6, e7)
#undef CMPEX
    kb[x] = e0; kb[x + jq] = e1; kb[x + 2 * jq] = e2; kb[x + 3 * jq] = e3;
    kb[x + 4 * jq] = e4; kb[x + 5 * jq] = e5; kb[x + 6 * jq] = e6; kb[x + 7 * jq] = e7;
}

// 4 fused levels (j, j/2, j/4, j/8) via 16-element gather at stride jq=j/8.
__global__ __launch_bounds__(256) void bitonic_global_fused4(uint64_t* __restrict__ keys,
                                                             int k, int j) {
    int tid = blockIdx.x * 256 + threadIdx.x;
    const int q = NELEM / 16;
    int b = tid / q;
    int tt = tid - b * q;
    int jq = j >> 3;
    int x = ((tt & ~(jq - 1)) << 4) | (tt & (jq - 1));
    uint64_t* kb = keys + (size_t)b * NELEM;
    bool ddd = ((x & k) == 0);
    uint64_t e[16];
#pragma unroll
    for (int i = 0; i < 16; ++i) e[i] = kb[x + i * jq];
    uint64_t tmp;
#define CMPEX(A, B) { bool sw = ddd ? (e[A] < e[B]) : (e[A] > e[B]); \
    if (sw) { tmp = e[A]; e[A] = e[B]; e[B] = tmp; } }
#pragma unroll
    for (int i = 0; i < 8; ++i) CMPEX(i, i + 8)
#pragma unroll
    for (int g2 = 0; g2 < 16; g2 += 8) {
        CMPEX(g2 + 0, g2 + 4) CMPEX(g2 + 1, g2 + 5) CMPEX(g2 + 2, g2 + 6) CMPEX(g2 + 3, g2 + 7)
    }
#pragma unroll
    for (int g2 = 0; g2 < 16; g2 += 4) { CMPEX(g2 + 0, g2 + 2) CMPEX(g2 + 1, g2 + 3) }
#pragma unroll
    for (int g2 = 0; g2 < 16; g2 += 2) CMPEX(g2, g2 + 1)
#undef CMPEX
#pragma unroll
    for (int i = 0; i < 16; ++i) kb[x + i * jq] = e[i];
}

__global__ __launch_bounds__(1024) void bitonic_local_merge8(uint64_t* __restrict__ keys,
                                                             int k) {
    __shared__ uint64_t sh[8192];
    const int t = threadIdx.x;
    const size_t base = (size_t)blockIdx.x * 8192;
    for (int e = t; e < 8192; e += 1024) sh[e] = keys[base + e];
    __syncthreads();
    const bool ddd = (((int)(base & (NELEM - 1)) & k) == 0);
    for (int j = 4096; j >= 1; j >>= 1) {
        for (int pp = t; pp < 4096; pp += 1024) {
            int a = ((pp & ~(j - 1)) << 1) | (pp & (j - 1));
            uint64_t x = sh[a], y = sh[a + j];
            bool sw = ddd ? (x < y) : (x > y);
            if (sw) { sh[a] = y; sh[a + j] = x; }
        }
        __syncthreads();
    }
    for (int e = t; e < 8192; e += 1024) keys[base + e] = sh[e];
}

__global__ __launch_bounds__(256) void sort_check(const uint64_t* __restrict__ keys,
                                                  uint32_t* __restrict__ flag) {
    int i = blockIdx.x * 256 + threadIdx.x;
    if (i >= BATCH * NELEM) return;
    uint32_t q = (uint32_t)i & (NELEM - 1);
    if (q != NELEM - 1) {
        if (keys[i] < keys[i + 1]) atomicOr(flag, 1u);
    }
}

// ---- packed candidate records for top-M; zero kcount ------------------------
__global__ __launch_bounds__(256) void records_kernel(
    const uint64_t* __restrict__ keys, const float* __restrict__ deltas,
    const float* __restrict__ anchors, const float* __restrict__ logits,
    float* __restrict__ records, uint32_t* __restrict__ kcount, int M) {
    int g = blockIdx.x * 256 + threadIdx.x;
    if (g >= BATCH * M) return;
    kcount[g] = 0;
    int b = g / M, r = g - b * M;
    uint64_t key = keys[(size_t)b * NELEM + r];
    float4 r0, r1;
    if (key != 0) {
        uint32_t idx = (uint32_t)((~key) & 0x1FFFFu);
        size_t gi = (size_t)b * NELEM + idx;
        float bx[4];
        decode_f(deltas, anchors, gi, bx);
        r0 = make_float4(bx[0], bx[1], bx[2], bx[3]);
        r1 = make_float4(score_f(logits, gi), logits[2 * gi], logits[2 * gi + 1], 1.0f);
    } else {
        r0 = make_float4(0.f, 0.f, 0.f, 0.f);
        r1 = make_float4(0.f, 0.f, 0.f, 0.f);
    }
    float4* rp = (float4*)records;
    rp[(size_t)g * 2] = r0;
    rp[(size_t)g * 2 + 1] = r1;
}

// ---- kill masks: dense rows (overflow fallback) + sparse killer lists -------
__global__ __launch_bounds__(64) void mask_kernel(const float* __restrict__ records,
                                                  uint64_t* __restrict__ masks,
                                                  uint32_t* __restrict__ kcount,
                                                  uint16_t* __restrict__ klist, int M) {
    int ti = blockIdx.x, tj = blockIdx.y, b = blockIdx.z;
    if (tj > ti) return;
    int t = threadIdx.x;
    __shared__ float4 jb[64];
    __shared__ int jv[64];
    const float4* rp = (const float4*)records;
    {
        float4 rj  = rp[((size_t)b * M + (size_t)tj * 64 + t) * 2];
        float4 rj1 = rp[((size_t)b * M + (size_t)tj * 64 + t) * 2 + 1];
        jb[t] = rj;
        jv[t] = (rj1.w != 0.f);
    }
    const int i = ti * 64 + t;
    float4 ri  = rp[((size_t)b * M + i) * 2];
    float4 ri1 = rp[((size_t)b * M + i) * 2 + 1];
    bool iv = (ri1.w != 0.f);
    __syncthreads();
    uint64_t word = 0;
    if (iv) {
        for (int jj = 0; jj < 64; ++jj) {
            bool earlier = (tj < ti) || (jj < t);
            if (earlier && jv[jj] && maybe4(jb[jj], ri) && iou_gt4(jb[jj], ri)) {
                word |= 1ull << jj;
                uint32_t slot = atomicAdd(&kcount[(size_t)b * M + i], 1u);
                if (slot < KCAP)
                    klist[((size_t)b * M + i) * KCAP + slot] = (uint16_t)(tj * 64 + jj);
            }
        }
    }
    masks[((size_t)b * M + i) * (size_t)(M >> 6) + tj] = word;
}

// ---- G1: sparse-list greedy walk, CHUNK=256, bulk-accept scan ---------------
__global__ void nms_walk(
    const float* __restrict__ records, const uint64_t* __restrict__ masks,
    const uint32_t* __restrict__ kcount, const uint16_t* __restrict__ klist,
    float4* __restrict__ accbox, uint32_t* __restrict__ state,
    float* __restrict__ out, int M) {
    const int b = blockIdx.x;
    const int t = threadIdx.x;
    const int Wm = M >> 6;
    const int NC = M >> 8;
    const uint64_t* mb = masks + (size_t)b * M * (size_t)Wm;
    const float4* rp = (const float4*)records + (size_t)b * M * 2;

    __shared__ uint64_t accset[128];
    __shared__ uint64_t bwLDS[256][4];
    __shared__ uint8_t kf[256];
    __shared__ float4 recLDS[512];
    __shared__ uint32_t s_state[16];

    for (int w = t; w < 128; w += blockDim.x) accset[w] = 0;
    __syncthreads();

    int n_acc = 0, done = 0;
    for (int ci = 0; ci < NC && !done; ++ci) {
        const int p = ci << 8;
        const int pw = ci << 2;
        if (t < 256) {
            const int gi = p + t;
            uint32_t cnt = kcount[(size_t)b * M + gi];
            uint64_t rq0 = 0, rq1 = 0, rq2 = 0, rq3 = 0;
            bool kill = false;
            if (cnt <= KCAP) {
                const uint16_t* lp = klist + ((size_t)b * M + gi) * KCAP;
                for (uint32_t u = 0; u < cnt; ++u) {
                    int j = lp[u];
                    if (j < p) {
                        if ((accset[j >> 6] >> (j & 63)) & 1) kill = true;
                    } else {
                        int d = j - p;
                        uint64_t bit = 1ull << (d & 63);
                        switch (d >> 6) {
                            case 0: rq0 |= bit; break;
                            case 1: rq1 |= bit; break;
                            case 2: rq2 |= bit; break;
                            default: rq3 |= bit; break;
                        }
                    }
                }
            } else {
                const uint64_t* row = mb + (size_t)gi * Wm;
                uint64_t o = 0;
                for (int w = 0; w < pw; ++w) o |= row[w] & accset[w];
                kill = (o != 0);
                rq0 = row[pw]; rq1 = row[pw + 1];
                rq2 = row[pw + 2]; rq3 = row[pw + 3];
            }
            kf[t] = kill ? 1 : 0;
            bwLDS[t][0] = rq0; bwLDS[t][1] = rq1;
            bwLDS[t][2] = rq2; bwLDS[t][3] = rq3;
        } else if (t < 512) {
            int i0 = t - 256;
            recLDS[i0] = rp[(size_t)p * 2 + i0];
            recLDS[i0 + 256] = rp[(size_t)p * 2 + i0 + 256];
        }
        __syncthreads();

        // D: wave 0 — bulk accept + short serial resolution of conflicted rows
        if (t < 64) {
            const int l = t;
            uint64_t b00 = bwLDS[l][0], b01 = bwLDS[l][1], b02 = bwLDS[l][2], b03 = bwLDS[l][3];
            uint64_t b10 = bwLDS[64 + l][0], b11 = bwLDS[64 + l][1], b12 = bwLDS[64 + l][2], b13 = bwLDS[64 + l][3];
            uint64_t b20 = bwLDS[128 + l][0], b21 = bwLDS[128 + l][1], b22 = bwLDS[128 + l][2], b23 = bwLDS[128 + l][3];
            uint64_t b30 = bwLDS[192 + l][0], b31 = bwLDS[192 + l][1], b32 = bwLDS[192 + l][2], b33 = bwLDS[192 + l][3];
            uint64_t vm0 = __ballot(recLDS[2 * l + 1].w != 0.f);
            uint64_t vm1 = __ballot(recLDS[2 * (64 + l) + 1].w != 0.f);
            uint64_t vm2 = __ballot(recLDS[2 * (128 + l) + 1].w != 0.f);
            uint64_t vm3 = __ballot(recLDS[2 * (192 + l) + 1].w != 0.f);
            uint64_t k0 = __ballot(kf[l] != 0);
            uint64_t k1 = __ballot(kf[64 + l] != 0);
            uint64_t k2 = __ballot(kf[128 + l] != 0);
            uint64_t k3 = __ballot(kf[192 + l] != 0);
            uint64_t e0m = __ballot((b00 | b01 | b02 | b03) == 0);
            uint64_t e1m = __ballot((b10 | b11 | b12 | b13) == 0);
            uint64_t e2m = __ballot((b20 | b21 | b22 | b23) == 0);
            uint64_t e3m = __ballot((b30 | b31 | b32 | b33) == 0);
            if (t == 0) {
                uint64_t t0 = vm0 & ~k0, t1 = vm1 & ~k1, t2 = vm2 & ~k2, t3 = vm3 & ~k3;
                uint64_t a0 = t0 & e0m, a1 = t1 & e1m, a2 = t2 & e2m, a3 = t3 & e3m;
                uint64_t c0 = t0 & ~e0m, c1 = t1 & ~e1m, c2 = t2 & ~e2m, c3 = t3 & ~e3m;
#define RESOLVE(cq, aq, base) \
    while (cq) { int cb = __builtin_ctzll(cq); cq &= cq - 1; \
        int idx = (base) + cb; \
        uint64_t w0 = bwLDS[idx][0], w1 = bwLDS[idx][1]; \
        uint64_t w2 = bwLDS[idx][2], w3 = bwLDS[idx][3]; \
        if (!((w0 & a0) | (w1 & a1) | (w2 & a2) | (w3 & a3))) aq |= (1ull << cb); }
                RESOLVE(c0, a0, 0)
                RESOLVE(c1, a1, 64)
                RESOLVE(c2, a2, 128)
                RESOLVE(c3, a3, 192)
#undef RESOLVE
                int n = n_acc;
                int dn = ((vm0 & vm1 & vm2 & vm3) != ~0ull) ? 1 : 0;
                int tot = (int)(__popcll(a0) + __popcll(a1) + __popcll(a2) + __popcll(a3));
                int rem = OUT_NUM - n;
                if (tot >= rem) {   // exact keep-first-rem truncation
                    int keep = rem;
#define TRUNC(w) { int pc = (int)__popcll(w); \
    if (keep >= pc) keep -= pc; \
    else { while ((int)__popcll(w) > keep) w &= ~(1ull << (63 - __builtin_clzll(w))); keep = 0; } }
                    TRUNC(a0) TRUNC(a1) TRUNC(a2) TRUNC(a3)
#undef TRUNC
                    n = OUT_NUM; dn = 1;
                } else {
                    n += tot;
                }
                s_state[0] = (uint32_t)n_acc;
                s_state[1] = (uint32_t)n;
                s_state[2] = (uint32_t)dn;
                s_state[3] = (uint32_t)a0; s_state[4] = (uint32_t)(a0 >> 32);
                s_state[5] = (uint32_t)a1; s_state[6] = (uint32_t)(a1 >> 32);
                s_state[7] = (uint32_t)a2; s_state[8] = (uint32_t)(a2 >> 32);
                s_state[9] = (uint32_t)a3; s_state[10] = (uint32_t)(a3 >> 32);
                accset[pw] = a0; accset[pw + 1] = a1;
                accset[pw + 2] = a2; accset[pw + 3] = a3;
            }
        }
        __syncthreads();
        int r0 = (int)s_state[0];
        n_acc = (int)s_state[1];
        done = (int)s_state[2];
        uint64_t amA = ((uint64_t)s_state[4] << 32) | s_state[3];
        uint64_t amB = ((uint64_t)s_state[6] << 32) | s_state[5];
        uint64_t amC = ((uint64_t)s_state[8] << 32) | s_state[7];
        uint64_t amD = ((uint64_t)s_state[10] << 32) | s_state[9];

        if (t < 256) {
            int q = t >> 6, ll = t & 63;
            uint64_t amq = q == 0 ? amA : q == 1 ? amB : q == 2 ? amC : amD;
            if ((amq >> ll) & 1) {
                int base = r0;
                if (q > 0) base += (int)__popcll(amA);
                if (q > 1) base += (int)__popcll(amB);
                if (q > 2) base += (int)__popcll(amC);
                int row = base + (int)__popcll(amq & ((1ull << ll) - 1ull));
                float4 cb = recLDS[t * 2], cm = recLDS[t * 2 + 1];
                accbox[(size_t)b * OUT_NUM + row] = cb;
                float* ob = out + ((size_t)b * OUT_NUM + row) * 5;
                ob[0] = cb.x; ob[1] = cb.y; ob[2] = cb.z; ob[3] = cb.w; ob[4] = 1.0f;
                float* os = out + (size_t)BATCH * OUT_NUM * 5 +
                            ((size_t)b * OUT_NUM + row) * 2;
                os[0] = cm.x; os[1] = 1.0f;
                float* ol = out + (size_t)BATCH * OUT_NUM * 7 +
                            ((size_t)b * OUT_NUM + row) * 3;
                ol[0] = cm.y; ol[1] = cm.z; ol[2] = 1.0f;
            }
        }
        __syncthreads();
    }
    if (t == 0) {
        state[b * 16] = (uint32_t)n_acc;
        state[b * 16 + 1] = (uint32_t)done;
    }
}

// ---- prekill (round-13 form): aF-only LDS, 1024 threads, 16 thr/candidate ---
__global__ __launch_bounds__(1024) void prekill_kernel(
    const uint64_t* __restrict__ keys, const float* __restrict__ deltas,
    const float* __restrict__ anchors, const float4* __restrict__ accbox,
    const uint32_t* __restrict__ state, uint64_t* __restrict__ kpre, int Mend) {
    const int blk = blockIdx.x, b = blockIdx.y;
    const int t = threadIdx.x;
    const int c = t & 63, g = t >> 6;   // 16 threads per candidate
    const int n1 = (int)state[b * 16];
    __shared__ float4 aF[OUT_NUM];      // 32 KB
    __shared__ float4 jb[64];
    __shared__ uint8_t kfl[64];
    for (int r = t; r < n1; r += 1024) aF[r] = accbox[(size_t)b * OUT_NUM + r];
    if (t < 64) {
        kfl[t] = 0;
        int j = Mend + blk * 64 + t;
        uint64_t key = keys[(size_t)b * NELEM + j];
        float4 bx4 = make_float4(0.f, 0.f, 0.f, 0.f);
        if (key != 0) {
            uint32_t idx = (uint32_t)((~key) & 0x1FFFFu);
            size_t gi = (size_t)b * NELEM + idx;
            float bx[4];
            decode_f(deltas, anchors, gi, bx);
            bx4 = make_float4(bx[0], bx[1], bx[2], bx[3]);
        }
        jb[t] = bx4;
    }
    __syncthreads();
    float4 cb = jb[c];
    float csy = cb.x + cb.z, csx = cb.y + cb.w;
    float ch19 = 0.19f * (cb.z - cb.x), cw19 = 0.19f * (cb.w - cb.y);
    bool k = false;
    for (int a = g; a < n1; a += 16) {
        float4 af = aF[a];
        float asy = af.x + af.z, asx = af.y + af.w;
        float ah19 = 0.19f * (af.z - af.x), aw19 = 0.19f * (af.w - af.y);
        if (fabsf(asy - csy) < ah19 + ch19 && fabsf(asx - csx) < aw19 + cw19) {
            if (iou_gt4(af, cb)) { k = true; break; }
        }
    }
    if (k) kfl[c] = 1;   // benign same-value race
    __syncthreads();
    if (t < 64) {
        uint64_t w = __ballot(kfl[t] != 0);
        if (t == 0) kpre[(size_t)b * KPRE_W + blk] = w;
    }
}

// ---- G2: tail beyond M, CHUNK=256, prekill window + full-scan fallback ------
__global__ __launch_bounds__(512) void nms_tail(
    const uint64_t* __restrict__ keys, const float* __restrict__ deltas,
    const float* __restrict__ logits, const float* __restrict__ anchors,
    const float4* __restrict__ accbox, const uint32_t* __restrict__ state,
    const uint64_t* __restrict__ kpre, float* __restrict__ out,
    int Mend, int hasPre) {
    const int b = blockIdx.x;
    const int t = threadIdx.x;
    const int l = t & 63;

    __shared__ float4 aF4[OUT_NUM];
    __shared__ float4 aS4[OUT_NUM];
    __shared__ float4 cbox[256], cmeta[256];
    __shared__ uint32_t transW[256][8];
    __shared__ uint8_t kf2[512];
    __shared__ uint64_t kpreLDS[4];
    __shared__ uint32_t s_state[16];

    if (t == 0) {
        s_state[0] = state[b * 16];
        s_state[1] = state[b * 16 + 1];
    }
    __syncthreads();
    int n_acc = (int)s_state[0];
    int done = (int)s_state[1];
    const int tailStart = n_acc;
    for (int r = t; r < n_acc; r += 512) {
        float4 ab = accbox[(size_t)b * OUT_NUM + r];
        aF4[r] = ab;
        aS4[r] = make_float4(ab.x + ab.z, ab.y + ab.w, ab.z - ab.x, ab.w - ab.y);
    }
    __syncthreads();

    for (int p = Mend; p < NELEM && !done; p += 256) {
        const bool inwin = hasPre && (p < Mend + PREWIN);
        for (int i = t; i < 2048; i += 512) ((uint32_t*)transW)[i] = 0;
        if (t < 256) {
            uint64_t key = keys[(size_t)b * NELEM + p + t];
            float4 bx4 = make_float4(0.f, 0.f, 0.f, 0.f);
            float4 mt = make_float4(0.f, 0.f, 0.f, 0.f);
            if (key != 0) {
                uint32_t idx = (uint32_t)((~key) & 0x1FFFFu);
                size_t gi = (size_t)b * NELEM + idx;
                float bx[4];
                decode_f(deltas, anchors, gi, bx);
                bx4 = make_float4(bx[0], bx[1], bx[2], bx[3]);
                mt = make_float4(score_f(logits, gi), logits[2 * gi],
                                 logits[2 * gi + 1], 1.0f);
            }
            cbox[t] = bx4; cmeta[t] = mt;
        }
        if (t < 4)
            kpreLDS[t] = inwin ? kpre[(size_t)b * KPRE_W + ((p - Mend) >> 6) + t] : 0ull;
        __syncthreads();

        // B: killed-by-accepted (within window: only tail-born accepts)
        {
            const int c = t & 255, g = t >> 8;
            float4 cb = cbox[c];
            bool pkc = inwin && ((kpreLDS[c >> 6] >> (c & 63)) & 1);
            bool valid = (cmeta[c].w != 0.f) && !pkc;
            float csy = cb.x + cb.z, csx = cb.y + cb.w;
            float chh = cb.z - cb.x, cww = cb.w - cb.y;
            bool k = false;
            int aStart = inwin ? tailStart : 0;
            if (valid) {
                for (int a = aStart + g; a < n_acc; a += 2) {
                    float4 as = aS4[a];
                    if (fabsf(as.x - csy) < 0.19f * (as.z + chh) &&
                        fabsf(as.y - csx) < 0.19f * (as.w + cww)) {
                        if (iou_gt4(aF4[a], cb)) { k = true; break; }
                    }
                }
            }
            kf2[t] = k ? 1 : 0;
        }
        __syncthreads();   // C sees B's kills, skips dead pairs

        // C: intra-chunk killers among survivors only
        for (int pid = t; pid < 256 * 256; pid += 512) {
            int c0 = pid >> 8, c1 = pid & 255;
            if (c1 > c0 && cmeta[c0].w != 0.f && cmeta[c1].w != 0.f) {
                bool d0 = (inwin && ((kpreLDS[c0 >> 6] >> (c0 & 63)) & 1)) ||
                          kf2[c0] || kf2[256 + c0];
                bool d1 = (inwin && ((kpreLDS[c1 >> 6] >> (c1 & 63)) & 1)) ||
                          kf2[c1] || kf2[256 + c1];
                if (!d0 && !d1 && maybe4(cbox[c0], cbox[c1]) &&
                    iou_gt4(cbox[c0], cbox[c1]))
                    atomicOr(&transW[c1][c0 >> 5], 1u << (c0 & 31));
            }
        }
        __syncthreads();

        // D: wave0 scan
        if (t < 64) {
            uint64_t bw00, bw01, bw02, bw03, bw10, bw11, bw12, bw13;
            uint64_t bw20, bw21, bw22, bw23, bw30, bw31, bw32, bw33;
            bw00 = ((uint64_t)transW[l][1] << 32) | transW[l][0];
            bw01 = ((uint64_t)transW[l][3] << 32) | transW[l][2];
            bw02 = ((uint64_t)transW[l][5] << 32) | transW[l][4];
            bw03 = ((uint64_t)transW[l][7] << 32) | transW[l][6];
            bw10 = ((uint64_t)transW[64 + l][1] << 32) | transW[64 + l][0];
            bw11 = ((uint64_t)transW[64 + l][3] << 32) | transW[64 + l][2];
            bw12 = ((uint64_t)transW[64 + l][5] << 32) | transW[64 + l][4];
            bw13 = ((uint64_t)transW[64 + l][7] << 32) | transW[64 + l][6];
            bw20 = ((uint64_t)transW[128 + l][1] << 32) | transW[128 + l][0];
            bw21 = ((uint64_t)transW[128 + l][3] << 32) | transW[128 + l][2];
            bw22 = ((uint64_t)transW[128 + l][5] << 32) | transW[128 + l][4];
            bw23 = ((uint64_t)transW[128 + l][7] << 32) | transW[128 + l][6];
            bw30 = ((uint64_t)transW[192 + l][1] << 32) | transW[192 + l][0];
            bw31 = ((uint64_t)transW[192 + l][3] << 32) | transW[192 + l][2];
            bw32 = ((uint64_t)transW[192 + l][5] << 32) | transW[192 + l][4];
            bw33 = ((uint64_t)transW[192 + l][7] << 32) | transW[192 + l][6];
            uint64_t vm0 = __ballot(cmeta[l].w != 0.f);
            uint64_t vm1 = __ballot(cmeta[64 + l].w != 0.f);
            uint64_t vm2 = __ballot(cmeta[128 + l].w != 0.f);
            uint64_t vm3 = __ballot(cmeta[192 + l].w != 0.f);
            uint64_t k0 = kpreLDS[0] | __ballot((kf2[l] | kf2[256 + l]) != 0);
            uint64_t k1 = kpreLDS[1] | __ballot((kf2[64 + l] | kf2[320 + l]) != 0);
            uint64_t k2 = kpreLDS[2] | __ballot((kf2[128 + l] | kf2[384 + l]) != 0);
            uint64_t k3 = kpreLDS[3] | __ballot((kf2[192 + l] | kf2[448 + l]) != 0);
            uint64_t t0 = vm0 & ~k0, t1 = vm1 & ~k1, t2 = vm2 & ~k2, t3 = vm3 & ~k3;
            uint64_t am0 = 0, am1 = 0, am2 = 0, am3 = 0;
            int n = n_acc;
            int dn = ((vm0 & vm1 & vm2 & vm3) != ~0ull);
            while (t0 | t1 | t2 | t3) {
                int qb; uint64_t w;
                if (t0)      { qb = 0; w = t0; }
                else if (t1) { qb = 1; w = t1; }
                else if (t2) { qb = 2; w = t2; }
                else         { qb = 3; w = t3; }
                int lb = __builtin_ctzll(w);
                uint64_t bit = 1ull << lb;
                if (qb == 0) { am0 |= bit; t0 &= ~bit; }
                else if (qb == 1) { am1 |= bit; t1 &= ~bit; }
                else if (qb == 2) { am2 |= bit; t2 &= ~bit; }
                else { am3 |= bit; t3 &= ~bit; }
                ++n;
                if (n == OUT_NUM) { dn = 1; break; }
                uint64_t s0 = qb == 0 ? bw00 : qb == 1 ? bw01 : qb == 2 ? bw02 : bw03;
                uint64_t s1 = qb == 0 ? bw10 : qb == 1 ? bw11 : qb == 2 ? bw12 : bw13;
                uint64_t s2 = qb == 0 ? bw20 : qb == 1 ? bw21 : qb == 2 ? bw22 : bw23;
                uint64_t s3 = qb == 0 ? bw30 : qb == 1 ? bw31 : qb == 2 ? bw32 : bw33;
                t0 &= ~__ballot(((s0 >> lb) & 1) != 0);
                t1 &= ~__ballot(((s1 >> lb) & 1) != 0);
                t2 &= ~__ballot(((s2 >> lb) & 1) != 0);
                t3 &= ~__ballot(((s3 >> lb) & 1) != 0);
            }
            if (t == 0) {
                s_state[0] = (uint32_t)n_acc;
                s_state[1] = (uint32_t)n;
                s_state[2] = (uint32_t)dn;
                s_state[3] = (uint32_t)am0; s_state[4] = (uint32_t)(am0 >> 32);
                s_state[5] = (uint32_t)am1; s_state[6] = (uint32_t)(am1 >> 32);
                s_state[7] = (uint32_t)am2; s_state[8] = (uint32_t)(am2 >> 32);
                s_state[9] = (uint32_t)am3; s_state[10] = (uint32_t)(am3 >> 32);
            }
        }
        __syncthreads();
        int r0 = (int)s_state[0];
        n_acc = (int)s_state[1];
        done = (int)s_state[2];
        uint64_t amA = ((uint64_t)s_state[4] << 32) | s_state[3];
        uint64_t amB = ((uint64_t)s_state[6] << 32) | s_state[5];
        uint64_t amC = ((uint64_t)s_state[8] << 32) | s_state[7];
        uint64_t amD = ((uint64_t)s_state[10] << 32) | s_state[9];

        if (t < 256) {
            int q = t >> 6, ll = t & 63;
            uint64_t amq = q == 0 ? amA : q == 1 ? amB : q == 2 ? amC : amD;
            if ((amq >> ll) & 1) {
                int base = r0;
                if (q > 0) base += (int)__popcll(amA);
                if (q > 1) base += (int)__popcll(amB);
                if (q > 2) base += (int)__popcll(amC);
                int row = base + (int)__popcll(amq & ((1ull << ll) - 1ull));
                float4 cb = cbox[t];
                float4 cm = cmeta[t];
                aF4[row] = cb;
                aS4[row] = make_float4(cb.x + cb.z, cb.y + cb.w,
                                       cb.z - cb.x, cb.w - cb.y);
                float* ob = out + ((size_t)b * OUT_NUM + row) * 5;
                ob[0] = cb.x; ob[1] = cb.y; ob[2] = cb.z; ob[3] = cb.w; ob[4] = 1.0f;
                float* os = out + (size_t)BATCH * OUT_NUM * 5 +
                            ((size_t)b * OUT_NUM + row) * 2;
                os[0] = cm.x; os[1] = 1.0f;
                float* ol = out + (size_t)BATCH * OUT_NUM * 7 +
                            ((size_t)b * OUT_NUM + row) * 3;
                ol[0] = cm.y; ol[1] = cm.z; ol[2] = 1.0f;
            }
        }
        __syncthreads();
    }

    for (int r = n_acc + t; r < OUT_NUM; r += 512) {
        float* ob = out + ((size_t)b * OUT_NUM + r) * 5;
        ob[0] = 0.f; ob[1] = 0.f; ob[2] = 0.f; ob[3] = 0.f; ob[4] = 0.f;
        float* os = out + (size_t)BATCH * OUT_NUM * 5 + ((size_t)b * OUT_NUM + r) * 2;
        os[0] = 0.f; os[1] = 0.f;
        float* ol = out + (size_t)BATCH * OUT_NUM * 7 + ((size_t)b * OUT_NUM + r) * 3;
        ol[0] = 0.f; ol[1] = 0.f; ol[2] = 0.f;
    }
    if (t == 0 && n_acc < OUT_NUM) out[0] = 2.0e5f;  // canary B
}

__global__ void canary_kernel(const uint32_t* __restrict__ flag, float* __restrict__ out,
                              int code) {
    if (code) { out[0] = 3.0e5f; return; }
    if (*flag) out[0] = 1.0e5f;
}

extern "C" void kernel_launch(void* const* d_in, const int* in_sizes, int n_in,
                              void* d_out, int out_size, void* d_ws, size_t ws_size,
                              hipStream_t stream) {
    const float* deltas  = (const float*)d_in[0];
    const float* logits  = (const float*)d_in[1];
    const float* anchors = (const float*)d_in[2];
    float* out = (float*)d_out;

    const size_t keysB = (size_t)BATCH * NELEM * 8;
    const size_t flagOff = keysB;
    const size_t stateOff = keysB + 256;
    const size_t kpreOff = keysB + 512;                       // 4 KB (PREWIN=16384)
    const size_t accOff = kpreOff + 8192;
    const size_t recOff = accOff + 65536;
    if (ws_size < recOff) {
        canary_kernel<<<1, 1, 0, stream>>>((const uint32_t*)d_ws, out, 1);
        return;
    }
    // tier select; walk block size encodes the tier for rocprof telemetry
    int M = 0, wbs = 512;
    const int tiers[3] = {8192, 4096, 2048};
    const int twbs[3]  = {512, 576, 640};
    for (int i = 0; i < 3; ++i) {
        int cand = tiers[i];
        size_t need = recOff + (size_t)BATCH * cand * 32 +
                      (size_t)BATCH * cand * (cand / 8) +
                      (size_t)BATCH * cand * 4 +
                      (size_t)BATCH * cand * KCAP * 2;
        if (ws_size >= need) { M = cand; wbs = twbs[i]; break; }
    }

    uint64_t* keys = (uint64_t*)d_ws;
    uint32_t* flag = (uint32_t*)((char*)d_ws + flagOff);
    uint32_t* state = (uint32_t*)((char*)d_ws + stateOff);
    uint64_t* kpre = (uint64_t*)((char*)d_ws + kpreOff);
    float4* accbox = (float4*)((char*)d_ws + accOff);
    float* records = (float*)((char*)d_ws + recOff);
    uint64_t* masks = (uint64_t*)((char*)d_ws + recOff + (size_t)BATCH * M * 32);
    uint32_t* kcount = (uint32_t*)((char*)masks + (size_t)BATCH * M * (M / 8));
    uint16_t* klist = (uint16_t*)((char*)kcount + (size_t)BATCH * M * 4);

    prep_kernel<<<(BATCH * NELEM) / 256, 256, 0, stream>>>(logits, keys, flag, state);

    bitonic_local_sort4<<<BATCH * NELEM / 4096, 1024, 0, stream>>>(keys);
    bitonic_local_merge8<<<BATCH * NELEM / 8192, 1024, 0, stream>>>(keys, 8192);
    bitonic_global_pass<<<(BATCH * NELEM / 2) / 256, 256, 0, stream>>>(keys, 16384, 8192);
    bitonic_local_merge8<<<BATCH * NELEM / 8192, 1024, 0, stream>>>(keys, 16384);
    bitonic_global_fused2<<<(BATCH * NELEM / 4) / 256, 256, 0, stream>>>(keys, 32768, 16384);
    bitonic_local_merge8<<<BATCH * NELEM / 8192, 1024, 0, stream>>>(keys, 32768);
    bitonic_global_fused3<<<(BATCH * NELEM / 8) / 256, 256, 0, stream>>>(keys, 65536, 32768);
    bitonic_local_merge8<<<BATCH * NELEM / 8192, 1024, 0, stream>>>(keys, 65536);
    bitonic_global_fused4<<<(BATCH * NELEM / 16) / 256, 256, 0, stream>>>(keys, 131072, 65536);
    bitonic_local_merge8<<<BATCH * NELEM / 8192, 1024, 0, stream>>>(keys, 131072);

    sort_check<<<(BATCH * NELEM) / 256, 256, 0, stream>>>(keys, flag);
    if (M > 0) {
        records_kernel<<<(BATCH * M) / 256, 256, 0, stream>>>(keys, deltas, anchors,
                                                              logits, records, kcount, M);
        dim3 mg(M / 64, M / 64, BATCH);
        mask_kernel<<<mg, 64, 0, stream>>>(records, masks, kcount, klist, M);
        nms_walk<<<BATCH, wbs, 0, stream>>>(records, masks, kcount, klist,
                                            accbox, state, out, M);
        dim3 pg(PREWIN / 64, BATCH);
        prekill_kernel<<<pg, 1024, 0, stream>>>(keys, deltas, anchors, accbox, state,
                                                kpre, M);
    }
    nms_tail<<<BATCH, 512, 0, stream>>>(keys, deltas, logits, anchors, accbox, state,
                                        kpre, out, M, (M > 0) ? 1 : 0);
    canary_kernel<<<1, 1, 0, stream>>>(flag, out, 0);
}

// Round 16
// 248.598 us; speedup vs baseline: 1.1815x; 1.1286x over previous
//
#include <hip/hip_runtime.h>
#include <stdint.h>
#include <stddef.h>

#define BATCH 2
#define NELEM 131072           // anchors per batch (2^17)
#define OUT_NUM 2000
#define KCAP 32
#define PREWIN 16384
#define KPRE_W (PREWIN / 64)

__device__ __forceinline__ float exp32cr(float x) { return (float)exp((double)x); }

// Decision "IoU > 0.7" bit-equivalent to numpy-f32 fl(inter/den) > 0.7f (validated
// absmax=0 for 10 rounds): multiply-compare, exact __fdiv_rn inside guard band.
__device__ __forceinline__ bool iou_gt(float by1, float bx1, float by2, float bx2,
                                       float cy1, float cx1, float cy2, float cx2) {
    float y1 = fmaxf(by1, cy1), x1 = fmaxf(bx1, cx1);
    float y2 = fminf(by2, cy2), x2 = fminf(bx2, cx2);
    float ih = __fsub_rn(y2, y1), iw = __fsub_rn(x2, x1);
    if (ih <= 0.0f || iw <= 0.0f) return false;
    float inter = __fmul_rn(ih, iw);
    float a1 = __fmul_rn(__fsub_rn(by2, by1), __fsub_rn(bx2, bx1));
    float a2 = __fmul_rn(__fsub_rn(cy2, cy1), __fsub_rn(cx2, cx1));
    float den = __fadd_rn(__fsub_rn(__fadd_rn(a1, a2), inter), 1e-8f);
    float rhs = __fmul_rn(0.7f, den);
    if (inter > __fmul_rn(rhs, 1.0001f)) return true;
    if (inter < __fmul_rn(rhs, 0.9999f)) return false;
    return __fdiv_rn(inter, den) > 0.7f;
}
__device__ __forceinline__ bool iou_gt4(float4 a, float4 c) {
    return iou_gt(a.x, a.y, a.z, a.w, c.x, c.y, c.z, c.w);
}

// NECESSARY condition for IoU>0.7 (validated absmax=0, rounds 6-15)
__device__ __forceinline__ bool maybe4(float4 A, float4 C) {
    float dy = fabsf((A.x + A.z) - (C.x + C.z));
    float dx = fabsf((A.y + A.w) - (C.y + C.w));
    float hs = (A.z - A.x) + (C.z - C.x);
    float ws = (A.w - A.y) + (C.w - C.y);
    return (dy < 0.19f * hs) && (dx < 0.19f * ws);
}

// f32 box decode mirroring numpy-f32 (no contraction, CR exp)
__device__ __forceinline__ void decode_f(const float* __restrict__ deltas,
                                         const float* __restrict__ anchors,
                                         size_t gi, float* bx) {
    float a0 = anchors[4 * gi], a1 = anchors[4 * gi + 1];
    float a2 = anchors[4 * gi + 2], a3 = anchors[4 * gi + 3];
    float h = __fsub_rn(a2, a0), w = __fsub_rn(a3, a1);
    float cy = __fmul_rn(__fadd_rn(a2, a0), 0.5f);
    float cx = __fmul_rn(__fadd_rn(a3, a1), 0.5f);
    float d0 = __fmul_rn(deltas[4 * gi], 0.1f);
    float d1 = __fmul_rn(deltas[4 * gi + 1], 0.1f);
    float d2 = __fmul_rn(deltas[4 * gi + 2], 0.2f);
    float d3 = __fmul_rn(deltas[4 * gi + 3], 0.2f);
    cy = __fadd_rn(cy, __fmul_rn(d0, h));
    cx = __fadd_rn(cx, __fmul_rn(d1, w));
    h = __fmul_rn(h, exp32cr(d2));
    w = __fmul_rn(w, exp32cr(d3));
    bx[0] = __fsub_rn(cy, __fmul_rn(h, 0.5f));
    bx[1] = __fsub_rn(cx, __fmul_rn(w, 0.5f));
    bx[2] = __fadd_rn(cy, __fmul_rn(h, 0.5f));
    bx[3] = __fadd_rn(cx, __fmul_rn(w, 0.5f));
}

__device__ __forceinline__ float score_f(const float* __restrict__ logits, size_t gi) {
    float l0 = logits[2 * gi], l1 = logits[2 * gi + 1];
    float m = fmaxf(l0, l1);
    float e0 = exp32cr(__fsub_rn(l0, m));
    float e1 = exp32cr(__fsub_rn(l1, m));
    return __fdiv_rn(e1, __fadd_rn(e0, e1));
}

// key = f32-score-bits << 17 | 17-bit ~idx ; zeroes flag + state
__global__ __launch_bounds__(256) void prep_kernel(
    const float* __restrict__ logits, uint64_t* __restrict__ keys,
    uint32_t* __restrict__ flag, uint32_t* __restrict__ state) {
    int i = blockIdx.x * 256 + threadIdx.x;
    if (i == 0) *flag = 0;
    if (i < 32) state[i] = 0;
    if (i >= BATCH * NELEM) return;
    float s = score_f(logits, (size_t)i);
    uint32_t idx = (uint32_t)(i & (NELEM - 1));
    uint64_t key = 0;
    if (s > 0.05f)
        key = ((uint64_t)__float_as_uint(s) << 17) | ((~idx) & 0x1FFFFu);
    keys[i] = key;
}

// ---- bitonic sort (descending per batch) ------------------------------------
__global__ __launch_bounds__(1024) void bitonic_local_sort4(uint64_t* __restrict__ keys) {
    __shared__ uint64_t sh[4096];
    const int t = threadIdx.x;
    const size_t base = (size_t)blockIdx.x * 4096;
    for (int e = t; e < 4096; e += 1024) sh[e] = keys[base + e];
    __syncthreads();
    const int gb = (int)(base & (NELEM - 1));
    for (int k = 2; k <= 4096; k <<= 1) {
        for (int j = k >> 1; j >= 1; j >>= 1) {
            for (int pp = t; pp < 2048; pp += 1024) {
                int a = ((pp & ~(j - 1)) << 1) | (pp & (j - 1));
                bool ddd = (((gb + a) & k) == 0);
                uint64_t x = sh[a], y = sh[a + j];
                bool sw = ddd ? (x < y) : (x > y);
                if (sw) { sh[a] = y; sh[a + j] = x; }
            }
            __syncthreads();
        }
    }
    for (int e = t; e < 4096; e += 1024) keys[base + e] = sh[e];
}

__global__ __launch_bounds__(256) void bitonic_global_pass(uint64_t* __restrict__ keys,
                                                           int k, int j) {
    int tid = blockIdx.x * blockDim.x + threadIdx.x;
    const int half = NELEM / 2;
    int b = tid / half;
    int tt = tid - b * half;
    int a = ((tt & ~(j - 1)) << 1) | (tt & (j - 1));
    uint64_t* kb = keys + (size_t)b * NELEM;
    bool ddd = ((a & k) == 0);
    uint64_t x = kb[a], y = kb[a + j];
    bool sw = ddd ? (x < y) : (x > y);
    if (sw) { kb[a] = y; kb[a + j] = x; }
}

__global__ __launch_bounds__(256) void bitonic_global_fused2(uint64_t* __restrict__ keys,
                                                             int k, int j) {
    int tid = blockIdx.x * 256 + threadIdx.x;
    const int q = NELEM / 4;
    int b = tid / q;
    int tt = tid - b * q;
    int jh = j >> 1;
    int x = ((tt & ~(jh - 1)) << 2) | (tt & (jh - 1));
    uint64_t* kb = keys + (size_t)b * NELEM;
    bool ddd = ((x & k) == 0);
    uint64_t e0 = kb[x], e1 = kb[x + jh], e2 = kb[x + j], e3 = kb[x + j + jh];
    uint64_t tmp;
#define CMPEX(A, B) { bool sw = ddd ? (A < B) : (A > B); if (sw) { tmp = A; A = B; B = tmp; } }
    CMPEX(e0, e2) CMPEX(e1, e3)
    CMPEX(e0, e1) CMPEX(e2, e3)
#undef CMPEX
    kb[x] = e0; kb[x + jh] = e1; kb[x + j] = e2; kb[x + j + jh] = e3;
}

// 3 fused levels (j, j/2, j/4) via 8-element gather at stride jq=j/4.
__global__ __launch_bounds__(256) void bitonic_global_fused3(uint64_t* __restrict__ keys,
                                                             int k, int j) {
    int tid = blockIdx.x * 256 + threadIdx.x;
    const int q = NELEM / 8;
    int b = tid / q;
    int tt = tid - b * q;
    int jq = j >> 2;
    int x = ((tt & ~(jq - 1)) << 3) | (tt & (jq - 1));
    uint64_t* kb = keys + (size_t)b * NELEM;
    bool ddd = ((x & k) == 0);
    uint64_t e0 = kb[x], e1 = kb[x + jq], e2 = kb[x + 2 * jq], e3 = kb[x + 3 * jq];
    uint64_t e4 = kb[x + 4 * jq], e5 = kb[x + 5 * jq], e6 = kb[x + 6 * jq], e7 = kb[x + 7 * jq];
    uint64_t tmp;
#define CMPEX(A, B) { bool sw = ddd ? (A < B) : (A > B); if (sw) { tmp = A; A = B; B = tmp; } }
    CMPEX(e0, e4) CMPEX(e1, e5) CMPEX(e2, e6) CMPEX(e3, e7)
    CMPEX(e0, e2) CMPEX(e1, e3) CMPEX(e4, e6) CMPEX(e5, e7)
    CMPEX(e0, e1) CMPEX(e2, e3) CMPEX(e4, e5) CMPEX(e6, e7)
#undef CMPEX
    kb[x] = e0; kb[x + jq] = e1; kb[x + 2 * jq] = e2; kb[x + 3 * jq] = e3;
    kb[x + 4 * jq] = e4; kb[x + 5 * jq] = e5; kb[x + 6 * jq] = e6; kb[x + 7 * jq] = e7;
}

// 4 fused levels (j, j/2, j/4, j/8) via 16-element gather at stride jq=j/8.
__global__ __launch_bounds__(256) void bitonic_global_fused4(uint64_t* __restrict__ keys,
                                                             int k, int j) {
    int tid = blockIdx.x * 256 + threadIdx.x;
    const int q = NELEM / 16;
    int b = tid / q;
    int tt = tid - b * q;
    int jq = j >> 3;
    int x = ((tt & ~(jq - 1)) << 4) | (tt & (jq - 1));
    uint64_t* kb = keys + (size_t)b * NELEM;
    bool ddd = ((x & k) == 0);
    uint64_t e[16];
#pragma unroll
    for (int i = 0; i < 16; ++i) e[i] = kb[x + i * jq];
    uint64_t tmp;
#define CMPEX(A, B) { bool sw = ddd ? (e[A] < e[B]) : (e[A] > e[B]); \
    if (sw) { tmp = e[A]; e[A] = e[B]; e[B] = tmp; } }
#pragma unroll
    for (int i = 0; i < 8; ++i) CMPEX(i, i + 8)
#pragma unroll
    for (int g2 = 0; g2 < 16; g2 += 8) {
        CMPEX(g2 + 0, g2 + 4) CMPEX(g2 + 1, g2 + 5) CMPEX(g2 + 2, g2 + 6) CMPEX(g2 + 3, g2 + 7)
    }
#pragma unroll
    for (int g2 = 0; g2 < 16; g2 += 4) { CMPEX(g2 + 0, g2 + 2) CMPEX(g2 + 1, g2 + 3) }
#pragma unroll
    for (int g2 = 0; g2 < 16; g2 += 2) CMPEX(g2, g2 + 1)
#undef CMPEX
#pragma unroll
    for (int i = 0; i < 16; ++i) kb[x + i * jq] = e[i];
}

__global__ __launch_bounds__(1024) void bitonic_local_merge8(uint64_t* __restrict__ keys,
                                                             int k) {
    __shared__ uint64_t sh[8192];
    const int t = threadIdx.x;
    const size_t base = (size_t)blockIdx.x * 8192;
    for (int e = t; e < 8192; e += 1024) sh[e] = keys[base + e];
    __syncthreads();
    const bool ddd = (((int)(base & (NELEM - 1)) & k) == 0);
    for (int j = 4096; j >= 1; j >>= 1) {
        for (int pp = t; pp < 4096; pp += 1024) {
            int a = ((pp & ~(j - 1)) << 1) | (pp & (j - 1));
            uint64_t x = sh[a], y = sh[a + j];
            bool sw = ddd ? (x < y) : (x > y);
            if (sw) { sh[a] = y; sh[a + j] = x; }
        }
        __syncthreads();
    }
    for (int e = t; e < 8192; e += 1024) keys[base + e] = sh[e];
}

__global__ __launch_bounds__(256) void sort_check(const uint64_t* __restrict__ keys,
                                                  uint32_t* __restrict__ flag) {
    int i = blockIdx.x * 256 + threadIdx.x;
    if (i >= BATCH * NELEM) return;
    uint32_t q = (uint32_t)i & (NELEM - 1);
    if (q != NELEM - 1) {
        if (keys[i] < keys[i + 1]) atomicOr(flag, 1u);
    }
}

// ---- packed candidate records for top-M; zero kcount ------------------------
__global__ __launch_bounds__(256) void records_kernel(
    const uint64_t* __restrict__ keys, const float* __restrict__ deltas,
    const float* __restrict__ anchors, const float* __restrict__ logits,
    float* __restrict__ records, uint32_t* __restrict__ kcount, int M) {
    int g = blockIdx.x * 256 + threadIdx.x;
    if (g >= BATCH * M) return;
    kcount[g] = 0;
    int b = g / M, r = g - b * M;
    uint64_t key = keys[(size_t)b * NELEM + r];
    float4 r0, r1;
    if (key != 0) {
        uint32_t idx = (uint32_t)((~key) & 0x1FFFFu);
        size_t gi = (size_t)b * NELEM + idx;
        float bx[4];
        decode_f(deltas, anchors, gi, bx);
        r0 = make_float4(bx[0], bx[1], bx[2], bx[3]);
        r1 = make_float4(score_f(logits, gi), logits[2 * gi], logits[2 * gi + 1], 1.0f);
    } else {
        r0 = make_float4(0.f, 0.f, 0.f, 0.f);
        r1 = make_float4(0.f, 0.f, 0.f, 0.f);
    }
    float4* rp = (float4*)records;
    rp[(size_t)g * 2] = r0;
    rp[(size_t)g * 2 + 1] = r1;
}

// ---- kill masks: dense rows (overflow fallback) + sparse killer lists -------
__global__ __launch_bounds__(64) void mask_kernel(const float* __restrict__ records,
                                                  uint64_t* __restrict__ masks,
                                                  uint32_t* __restrict__ kcount,
                                                  uint16_t* __restrict__ klist, int M) {
    int ti = blockIdx.x, tj = blockIdx.y, b = blockIdx.z;
    if (tj > ti) return;
    int t = threadIdx.x;
    __shared__ float4 jb[64];
    __shared__ int jv[64];
    const float4* rp = (const float4*)records;
    {
        float4 rj  = rp[((size_t)b * M + (size_t)tj * 64 + t) * 2];
        float4 rj1 = rp[((size_t)b * M + (size_t)tj * 64 + t) * 2 + 1];
        jb[t] = rj;
        jv[t] = (rj1.w != 0.f);
    }
    const int i = ti * 64 + t;
    float4 ri  = rp[((size_t)b * M + i) * 2];
    float4 ri1 = rp[((size_t)b * M + i) * 2 + 1];
    bool iv = (ri1.w != 0.f);
    __syncthreads();
    uint64_t word = 0;
    if (iv) {
        for (int jj = 0; jj < 64; ++jj) {
            bool earlier = (tj < ti) || (jj < t);
            if (earlier && jv[jj] && maybe4(jb[jj], ri) && iou_gt4(jb[jj], ri)) {
                word |= 1ull << jj;
                uint32_t slot = atomicAdd(&kcount[(size_t)b * M + i], 1u);
                if (slot < KCAP)
                    klist[((size_t)b * M + i) * KCAP + slot] = (uint16_t)(tj * 64 + jj);
            }
        }
    }
    masks[((size_t)b * M + i) * (size_t)(M >> 6) + tj] = word;
}

// ---- G1: sparse-list greedy walk, CHUNK=256, bulk-accept scan ---------------
__global__ void nms_walk(
    const float* __restrict__ records, const uint64_t* __restrict__ masks,
    const uint32_t* __restrict__ kcount, const uint16_t* __restrict__ klist,
    float4* __restrict__ accbox, uint32_t* __restrict__ state,
    float* __restrict__ out, int M) {
    const int b = blockIdx.x;
    const int t = threadIdx.x;
    const int Wm = M >> 6;
    const int NC = M >> 8;
    const uint64_t* mb = masks + (size_t)b * M * (size_t)Wm;
    const float4* rp = (const float4*)records + (size_t)b * M * 2;

    __shared__ uint64_t accset[128];
    __shared__ uint64_t bwLDS[256][4];
    __shared__ uint8_t kf[256];
    __shared__ float4 recLDS[512];
    __shared__ uint32_t s_state[16];

    for (int w = t; w < 128; w += blockDim.x) accset[w] = 0;
    __syncthreads();

    int n_acc = 0, done = 0;
    for (int ci = 0; ci < NC && !done; ++ci) {
        const int p = ci << 8;
        const int pw = ci << 2;
        if (t < 256) {
            const int gi = p + t;
            uint32_t cnt = kcount[(size_t)b * M + gi];
            uint64_t rq0 = 0, rq1 = 0, rq2 = 0, rq3 = 0;
            bool kill = false;
            if (cnt <= KCAP) {
                const uint16_t* lp = klist + ((size_t)b * M + gi) * KCAP;
                for (uint32_t u = 0; u < cnt; ++u) {
                    int j = lp[u];
                    if (j < p) {
                        if ((accset[j >> 6] >> (j & 63)) & 1) kill = true;
                    } else {
                        int d = j - p;
                        uint64_t bit = 1ull << (d & 63);
                        switch (d >> 6) {
                            case 0: rq0 |= bit; break;
                            case 1: rq1 |= bit; break;
                            case 2: rq2 |= bit; break;
                            default: rq3 |= bit; break;
                        }
                    }
                }
            } else {
                const uint64_t* row = mb + (size_t)gi * Wm;
                uint64_t o = 0;
                for (int w = 0; w < pw; ++w) o |= row[w] & accset[w];
                kill = (o != 0);
                rq0 = row[pw]; rq1 = row[pw + 1];
                rq2 = row[pw + 2]; rq3 = row[pw + 3];
            }
            kf[t] = kill ? 1 : 0;
            bwLDS[t][0] = rq0; bwLDS[t][1] = rq1;
            bwLDS[t][2] = rq2; bwLDS[t][3] = rq3;
        } else if (t < 512) {
            int i0 = t - 256;
            recLDS[i0] = rp[(size_t)p * 2 + i0];
            recLDS[i0 + 256] = rp[(size_t)p * 2 + i0 + 256];
        }
        __syncthreads();

        // D: wave 0 — bulk accept + short serial resolution of conflicted rows
        if (t < 64) {
            const int l = t;
            uint64_t b00 = bwLDS[l][0], b01 = bwLDS[l][1], b02 = bwLDS[l][2], b03 = bwLDS[l][3];
            uint64_t b10 = bwLDS[64 + l][0], b11 = bwLDS[64 + l][1], b12 = bwLDS[64 + l][2], b13 = bwLDS[64 + l][3];
            uint64_t b20 = bwLDS[128 + l][0], b21 = bwLDS[128 + l][1], b22 = bwLDS[128 + l][2], b23 = bwLDS[128 + l][3];
            uint64_t b30 = bwLDS[192 + l][0], b31 = bwLDS[192 + l][1], b32 = bwLDS[192 + l][2], b33 = bwLDS[192 + l][3];
            uint64_t vm0 = __ballot(recLDS[2 * l + 1].w != 0.f);
            uint64_t vm1 = __ballot(recLDS[2 * (64 + l) + 1].w != 0.f);
            uint64_t vm2 = __ballot(recLDS[2 * (128 + l) + 1].w != 0.f);
            uint64_t vm3 = __ballot(recLDS[2 * (192 + l) + 1].w != 0.f);
            uint64_t k0 = __ballot(kf[l] != 0);
            uint64_t k1 = __ballot(kf[64 + l] != 0);
            uint64_t k2 = __ballot(kf[128 + l] != 0);
            uint64_t k3 = __ballot(kf[192 + l] != 0);
            uint64_t e0m = __ballot((b00 | b01 | b02 | b03) == 0);
            uint64_t e1m = __ballot((b10 | b11 | b12 | b13) == 0);
            uint64_t e2m = __ballot((b20 | b21 | b22 | b23) == 0);
            uint64_t e3m = __ballot((b30 | b31 | b32 | b33) == 0);
            if (t == 0) {
                uint64_t t0 = vm0 & ~k0, t1 = vm1 & ~k1, t2 = vm2 & ~k2, t3 = vm3 & ~k3;
                uint64_t a0 = t0 & e0m, a1 = t1 & e1m, a2 = t2 & e2m, a3 = t3 & e3m;
                uint64_t c0 = t0 & ~e0m, c1 = t1 & ~e1m, c2 = t2 & ~e2m, c3 = t3 & ~e3m;
#define RESOLVE(cq, aq, base) \
    while (cq) { int cb = __builtin_ctzll(cq); cq &= cq - 1; \
        int idx = (base) + cb; \
        uint64_t w0 = bwLDS[idx][0], w1 = bwLDS[idx][1]; \
        uint64_t w2 = bwLDS[idx][2], w3 = bwLDS[idx][3]; \
        if (!((w0 & a0) | (w1 & a1) | (w2 & a2) | (w3 & a3))) aq |= (1ull << cb); }
                RESOLVE(c0, a0, 0)
                RESOLVE(c1, a1, 64)
                RESOLVE(c2, a2, 128)
                RESOLVE(c3, a3, 192)
#undef RESOLVE
                int n = n_acc;
                int dn = ((vm0 & vm1 & vm2 & vm3) != ~0ull) ? 1 : 0;
                int tot = (int)(__popcll(a0) + __popcll(a1) + __popcll(a2) + __popcll(a3));
                int rem = OUT_NUM - n;
                if (tot >= rem) {   // exact keep-first-rem truncation
                    int keep = rem;
#define TRUNC(w) { int pc = (int)__popcll(w); \
    if (keep >= pc) keep -= pc; \
    else { while ((int)__popcll(w) > keep) w &= ~(1ull << (63 - __builtin_clzll(w))); keep = 0; } }
                    TRUNC(a0) TRUNC(a1) TRUNC(a2) TRUNC(a3)
#undef TRUNC
                    n = OUT_NUM; dn = 1;
                } else {
                    n += tot;
                }
                s_state[0] = (uint32_t)n_acc;
                s_state[1] = (uint32_t)n;
                s_state[2] = (uint32_t)dn;
                s_state[3] = (uint32_t)a0; s_state[4] = (uint32_t)(a0 >> 32);
                s_state[5] = (uint32_t)a1; s_state[6] = (uint32_t)(a1 >> 32);
                s_state[7] = (uint32_t)a2; s_state[8] = (uint32_t)(a2 >> 32);
                s_state[9] = (uint32_t)a3; s_state[10] = (uint32_t)(a3 >> 32);
                accset[pw] = a0; accset[pw + 1] = a1;
                accset[pw + 2] = a2; accset[pw + 3] = a3;
            }
        }
        __syncthreads();
        int r0 = (int)s_state[0];
        n_acc = (int)s_state[1];
        done = (int)s_state[2];
        uint64_t amA = ((uint64_t)s_state[4] << 32) | s_state[3];
        uint64_t amB = ((uint64_t)s_state[6] << 32) | s_state[5];
        uint64_t amC = ((uint64_t)s_state[8] << 32) | s_state[7];
        uint64_t amD = ((uint64_t)s_state[10] << 32) | s_state[9];

        if (t < 256) {
            int q = t >> 6, ll = t & 63;
            uint64_t amq = q == 0 ? amA : q == 1 ? amB : q == 2 ? amC : amD;
            if ((amq >> ll) & 1) {
                int base = r0;
                if (q > 0) base += (int)__popcll(amA);
                if (q > 1) base += (int)__popcll(amB);
                if (q > 2) base += (int)__popcll(amC);
                int row = base + (int)__popcll(amq & ((1ull << ll) - 1ull));
                float4 cb = recLDS[t * 2], cm = recLDS[t * 2 + 1];
                accbox[(size_t)b * OUT_NUM + row] = cb;
                float* ob = out + ((size_t)b * OUT_NUM + row) * 5;
                ob[0] = cb.x; ob[1] = cb.y; ob[2] = cb.z; ob[3] = cb.w; ob[4] = 1.0f;
                float* os = out + (size_t)BATCH * OUT_NUM * 5 +
                            ((size_t)b * OUT_NUM + row) * 2;
                os[0] = cm.x; os[1] = 1.0f;
                float* ol = out + (size_t)BATCH * OUT_NUM * 7 +
                            ((size_t)b * OUT_NUM + row) * 3;
                ol[0] = cm.y; ol[1] = cm.z; ol[2] = 1.0f;
            }
        }
        __syncthreads();
    }
    if (t == 0) {
        state[b * 16] = (uint32_t)n_acc;
        state[b * 16 + 1] = (uint32_t)done;
    }
}

// ---- accsort: sort walk-accepts by sy (order-independent consumers),
// compute ahmax, verify sortedness into canary flag --------------------------
__global__ __launch_bounds__(1024) void accsort_kernel(
    float4* __restrict__ accbox, uint32_t* __restrict__ state,
    uint32_t* __restrict__ flag) {
    const int b = blockIdx.x;
    const int t = threadIdx.x;
    const int n1 = (int)state[b * 16];
    __shared__ uint64_t sk[2048];
    __shared__ float4 tb[2048];
    __shared__ uint32_t s_hmax;
    if (t == 0) s_hmax = 0;
    float4* base = accbox + (size_t)b * OUT_NUM;
    for (int i = t; i < 2048; i += 1024) {
        uint64_t key = ~0ull;
        if (i < n1) {
            float4 ab = base[i];
            tb[i] = ab;
            uint32_t sb = __float_as_uint(ab.x + ab.z);
            sb = (sb & 0x80000000u) ? ~sb : (sb | 0x80000000u);  // order-preserving
            key = ((uint64_t)sb << 32) | (uint32_t)i;
        }
        sk[i] = key;
    }
    __syncthreads();
    for (int k = 2; k <= 2048; k <<= 1) {
        for (int j = k >> 1; j >= 1; j >>= 1) {
            int a = ((t & ~(j - 1)) << 1) | (t & (j - 1));
            bool up = ((a & k) == 0);
            uint64_t x = sk[a], y = sk[a + j];
            bool sw = up ? (x > y) : (x < y);
            if (sw) { sk[a] = y; sk[a + j] = x; }
            __syncthreads();
        }
    }
    uint32_t hm = 0;
    for (int i = t; i < n1; i += 1024) {
        float4 ab = tb[(uint32_t)(sk[i] & 0xFFFFFFFFu)];
        base[i] = ab;
        uint32_t hb = __float_as_uint(ab.z - ab.x);   // h >= 0 => uint-monotone
        hm = hm > hb ? hm : hb;
        if (i + 1 < n1 && (sk[i] >> 32) > (sk[i + 1] >> 32)) atomicOr(flag, 2u);
    }
    if (hm) atomicMax(&s_hmax, hm);
    __syncthreads();
    if (t == 0) state[b * 16 + 2] = s_hmax;
}

// ---- prekill v4: sy-sorted accepts + binary-search window -------------------
__global__ __launch_bounds__(1024) void prekill_kernel(
    const uint64_t* __restrict__ keys, const float* __restrict__ deltas,
    const float* __restrict__ anchors, const float4* __restrict__ accbox,
    const uint32_t* __restrict__ state, uint64_t* __restrict__ kpre, int Mend) {
    const int blk = blockIdx.x, b = blockIdx.y;
    const int t = threadIdx.x;
    const int c = t & 63, g = t >> 6;   // 16 threads per candidate
    const int n1 = (int)state[b * 16];
    const float ahmax = __uint_as_float(state[b * 16 + 2]);
    __shared__ float4 aF[OUT_NUM];      // 32 KB
    __shared__ float aSy[OUT_NUM];      // 8 KB
    __shared__ float4 jb[64];
    __shared__ uint8_t kfl[64];
    for (int r = t; r < n1; r += 1024) {
        float4 ab = accbox[(size_t)b * OUT_NUM + r];
        aF[r] = ab;
        aSy[r] = ab.x + ab.z;
    }
    if (t < 64) {
        kfl[t] = 0;
        int j = Mend + blk * 64 + t;
        uint64_t key = keys[(size_t)b * NELEM + j];
        float4 bx4 = make_float4(0.f, 0.f, 0.f, 0.f);
        if (key != 0) {
            uint32_t idx = (uint32_t)((~key) & 0x1FFFFu);
            size_t gi = (size_t)b * NELEM + idx;
            float bx[4];
            decode_f(deltas, anchors, gi, bx);
            bx4 = make_float4(bx[0], bx[1], bx[2], bx[3]);
        }
        jb[t] = bx4;
    }
    __syncthreads();
    float4 cb = jb[c];
    float csy = cb.x + cb.z, csx = cb.y + cb.w;
    float chh = cb.z - cb.x;
    float ch19 = 0.19f * chh, cw19 = 0.19f * (cb.w - cb.y);
    // conservative window: R = 0.2*(ahmax+ch) >= 0.19*(ah+ch) for all accepts
    float R = 0.2f * (ahmax + chh);
    float loV = csy - R, hiV = csy + R;
    int lo = 0, hi = n1;
    while (lo < hi) { int mid = (lo + hi) >> 1; if (aSy[mid] < loV) lo = mid + 1; else hi = mid; }
    const int i0 = lo;
    hi = n1;
    while (lo < hi) { int mid = (lo + hi) >> 1; if (aSy[mid] <= hiV) lo = mid + 1; else hi = mid; }
    const int i1 = lo;
    bool k = false;
    for (int a = i0 + g; a < i1; a += 16) {
        float4 af = aF[a];
        float asy = af.x + af.z, asx = af.y + af.w;
        float ah19 = 0.19f * (af.z - af.x), aw19 = 0.19f * (af.w - af.y);
        if (fabsf(asy - csy) < ah19 + ch19 && fabsf(asx - csx) < aw19 + cw19) {
            if (iou_gt4(af, cb)) { k = true; break; }
        }
    }
    if (k) kfl[c] = 1;   // benign same-value race
    __syncthreads();
    if (t < 64) {
        uint64_t w = __ballot(kfl[t] != 0);
        if (t == 0) kpre[(size_t)b * KPRE_W + blk] = w;
    }
}

// ---- G2: tail beyond M, CHUNK=256, prekill window + full-scan fallback ------
// (accbox now sy-sorted; order-independent here: set-membership IoU checks only)
__global__ __launch_bounds__(512) void nms_tail(
    const uint64_t* __restrict__ keys, const float* __restrict__ deltas,
    const float* __restrict__ logits, const float* __restrict__ anchors,
    const float4* __restrict__ accbox, const uint32_t* __restrict__ state,
    const uint64_t* __restrict__ kpre, float* __restrict__ out,
    int Mend, int hasPre) {
    const int b = blockIdx.x;
    const int t = threadIdx.x;
    const int l = t & 63;

    __shared__ float4 aF4[OUT_NUM];
    __shared__ float4 aS4[OUT_NUM];
    __shared__ float4 cbox[256], cmeta[256];
    __shared__ uint32_t transW[256][8];
    __shared__ uint8_t kf2[512];
    __shared__ uint64_t kpreLDS[4];
    __shared__ uint32_t s_state[16];

    if (t == 0) {
        s_state[0] = state[b * 16];
        s_state[1] = state[b * 16 + 1];
    }
    __syncthreads();
    int n_acc = (int)s_state[0];
    int done = (int)s_state[1];
    const int tailStart = n_acc;
    for (int r = t; r < n_acc; r += 512) {
        float4 ab = accbox[(size_t)b * OUT_NUM + r];
        aF4[r] = ab;
        aS4[r] = make_float4(ab.x + ab.z, ab.y + ab.w, ab.z - ab.x, ab.w - ab.y);
    }
    __syncthreads();

    for (int p = Mend; p < NELEM && !done; p += 256) {
        const bool inwin = hasPre && (p < Mend + PREWIN);
        for (int i = t; i < 2048; i += 512) ((uint32_t*)transW)[i] = 0;
        if (t < 256) {
            uint64_t key = keys[(size_t)b * NELEM + p + t];
            float4 bx4 = make_float4(0.f, 0.f, 0.f, 0.f);
            float4 mt = make_float4(0.f, 0.f, 0.f, 0.f);
            if (key != 0) {
                uint32_t idx = (uint32_t)((~key) & 0x1FFFFu);
                size_t gi = (size_t)b * NELEM + idx;
                float bx[4];
                decode_f(deltas, anchors, gi, bx);
                bx4 = make_float4(bx[0], bx[1], bx[2], bx[3]);
                mt = make_float4(score_f(logits, gi), logits[2 * gi],
                                 logits[2 * gi + 1], 1.0f);
            }
            cbox[t] = bx4; cmeta[t] = mt;
        }
        if (t < 4)
            kpreLDS[t] = inwin ? kpre[(size_t)b * KPRE_W + ((p - Mend) >> 6) + t] : 0ull;
        __syncthreads();

        // B: killed-by-accepted (within window: only tail-born accepts)
        {
            const int c = t & 255, g = t >> 8;
            float4 cb = cbox[c];
            bool pkc = inwin && ((kpreLDS[c >> 6] >> (c & 63)) & 1);
            bool valid = (cmeta[c].w != 0.f) && !pkc;
            float csy = cb.x + cb.z, csx = cb.y + cb.w;
            float chh = cb.z - cb.x, cww = cb.w - cb.y;
            bool k = false;
            int aStart = inwin ? tailStart : 0;
            if (valid) {
                for (int a = aStart + g; a < n_acc; a += 2) {
                    float4 as = aS4[a];
                    if (fabsf(as.x - csy) < 0.19f * (as.z + chh) &&
                        fabsf(as.y - csx) < 0.19f * (as.w + cww)) {
                        if (iou_gt4(aF4[a], cb)) { k = true; break; }
                    }
                }
            }
            kf2[t] = k ? 1 : 0;
        }
        __syncthreads();   // C sees B's kills, skips dead pairs

        // C: intra-chunk killers among survivors only
        for (int pid = t; pid < 256 * 256; pid += 512) {
            int c0 = pid >> 8, c1 = pid & 255;
            if (c1 > c0 && cmeta[c0].w != 0.f && cmeta[c1].w != 0.f) {
                bool d0 = (inwin && ((kpreLDS[c0 >> 6] >> (c0 & 63)) & 1)) ||
                          kf2[c0] || kf2[256 + c0];
                bool d1 = (inwin && ((kpreLDS[c1 >> 6] >> (c1 & 63)) & 1)) ||
                          kf2[c1] || kf2[256 + c1];
                if (!d0 && !d1 && maybe4(cbox[c0], cbox[c1]) &&
                    iou_gt4(cbox[c0], cbox[c1]))
                    atomicOr(&transW[c1][c0 >> 5], 1u << (c0 & 31));
            }
        }
        __syncthreads();

        // D: wave0 scan
        if (t < 64) {
            uint64_t bw00, bw01, bw02, bw03, bw10, bw11, bw12, bw13;
            uint64_t bw20, bw21, bw22, bw23, bw30, bw31, bw32, bw33;
            bw00 = ((uint64_t)transW[l][1] << 32) | transW[l][0];
            bw01 = ((uint64_t)transW[l][3] << 32) | transW[l][2];
            bw02 = ((uint64_t)transW[l][5] << 32) | transW[l][4];
            bw03 = ((uint64_t)transW[l][7] << 32) | transW[l][6];
            bw10 = ((uint64_t)transW[64 + l][1] << 32) | transW[64 + l][0];
            bw11 = ((uint64_t)transW[64 + l][3] << 32) | transW[64 + l][2];
            bw12 = ((uint64_t)transW[64 + l][5] << 32) | transW[64 + l][4];
            bw13 = ((uint64_t)transW[64 + l][7] << 32) | transW[64 + l][6];
            bw20 = ((uint64_t)transW[128 + l][1] << 32) | transW[128 + l][0];
            bw21 = ((uint64_t)transW[128 + l][3] << 32) | transW[128 + l][2];
            bw22 = ((uint64_t)transW[128 + l][5] << 32) | transW[128 + l][4];
            bw23 = ((uint64_t)transW[128 + l][7] << 32) | transW[128 + l][6];
            bw30 = ((uint64_t)transW[192 + l][1] << 32) | transW[192 + l][0];
            bw31 = ((uint64_t)transW[192 + l][3] << 32) | transW[192 + l][2];
            bw32 = ((uint64_t)transW[192 + l][5] << 32) | transW[192 + l][4];
            bw33 = ((uint64_t)transW[192 + l][7] << 32) | transW[192 + l][6];
            uint64_t vm0 = __ballot(cmeta[l].w != 0.f);
            uint64_t vm1 = __ballot(cmeta[64 + l].w != 0.f);
            uint64_t vm2 = __ballot(cmeta[128 + l].w != 0.f);
            uint64_t vm3 = __ballot(cmeta[192 + l].w != 0.f);
            uint64_t k0 = kpreLDS[0] | __ballot((kf2[l] | kf2[256 + l]) != 0);
            uint64_t k1 = kpreLDS[1] | __ballot((kf2[64 + l] | kf2[320 + l]) != 0);
            uint64_t k2 = kpreLDS[2] | __ballot((kf2[128 + l] | kf2[384 + l]) != 0);
            uint64_t k3 = kpreLDS[3] | __ballot((kf2[192 + l] | kf2[448 + l]) != 0);
            uint64_t t0 = vm0 & ~k0, t1 = vm1 & ~k1, t2 = vm2 & ~k2, t3 = vm3 & ~k3;
            uint64_t am0 = 0, am1 = 0, am2 = 0, am3 = 0;
            int n = n_acc;
            int dn = ((vm0 & vm1 & vm2 & vm3) != ~0ull);
            while (t0 | t1 | t2 | t3) {
                int qb; uint64_t w;
                if (t0)      { qb = 0; w = t0; }
                else if (t1) { qb = 1; w = t1; }
                else if (t2) { qb = 2; w = t2; }
                else         { qb = 3; w = t3; }
                int lb = __builtin_ctzll(w);
                uint64_t bit = 1ull << lb;
                if (qb == 0) { am0 |= bit; t0 &= ~bit; }
                else if (qb == 1) { am1 |= bit; t1 &= ~bit; }
                else if (qb == 2) { am2 |= bit; t2 &= ~bit; }
                else { am3 |= bit; t3 &= ~bit; }
                ++n;
                if (n == OUT_NUM) { dn = 1; break; }
                uint64_t s0 = qb == 0 ? bw00 : qb == 1 ? bw01 : qb == 2 ? bw02 : bw03;
                uint64_t s1 = qb == 0 ? bw10 : qb == 1 ? bw11 : qb == 2 ? bw12 : bw13;
                uint64_t s2 = qb == 0 ? bw20 : qb == 1 ? bw21 : qb == 2 ? bw22 : bw23;
                uint64_t s3 = qb == 0 ? bw30 : qb == 1 ? bw31 : qb == 2 ? bw32 : bw33;
                t0 &= ~__ballot(((s0 >> lb) & 1) != 0);
                t1 &= ~__ballot(((s1 >> lb) & 1) != 0);
                t2 &= ~__ballot(((s2 >> lb) & 1) != 0);
                t3 &= ~__ballot(((s3 >> lb) & 1) != 0);
            }
            if (t == 0) {
                s_state[0] = (uint32_t)n_acc;
                s_state[1] = (uint32_t)n;
                s_state[2] = (uint32_t)dn;
                s_state[3] = (uint32_t)am0; s_state[4] = (uint32_t)(am0 >> 32);
                s_state[5] = (uint32_t)am1; s_state[6] = (uint32_t)(am1 >> 32);
                s_state[7] = (uint32_t)am2; s_state[8] = (uint32_t)(am2 >> 32);
                s_state[9] = (uint32_t)am3; s_state[10] = (uint32_t)(am3 >> 32);
            }
        }
        __syncthreads();
        int r0 = (int)s_state[0];
        n_acc = (int)s_state[1];
        done = (int)s_state[2];
        uint64_t amA = ((uint64_t)s_state[4] << 32) | s_state[3];
        uint64_t amB = ((uint64_t)s_state[6] << 32) | s_state[5];
        uint64_t amC = ((uint64_t)s_state[8] << 32) | s_state[7];
        uint64_t amD = ((uint64_t)s_state[10] << 32) | s_state[9];

        if (t < 256) {
            int q = t >> 6, ll = t & 63;
            uint64_t amq = q == 0 ? amA : q == 1 ? amB : q == 2 ? amC : amD;
            if ((amq >> ll) & 1) {
                int base = r0;
                if (q > 0) base += (int)__popcll(amA);
                if (q > 1) base += (int)__popcll(amB);
                if (q > 2) base += (int)__popcll(amC);
                int row = base + (int)__popcll(amq & ((1ull << ll) - 1ull));
                float4 cb = cbox[t];
                float4 cm = cmeta[t];
                aF4[row] = cb;
                aS4[row] = make_float4(cb.x + cb.z, cb.y + cb.w,
                                       cb.z - cb.x, cb.w - cb.y);
                float* ob = out + ((size_t)b * OUT_NUM + row) * 5;
                ob[0] = cb.x; ob[1] = cb.y; ob[2] = cb.z; ob[3] = cb.w; ob[4] = 1.0f;
                float* os = out + (size_t)BATCH * OUT_NUM * 5 +
                            ((size_t)b * OUT_NUM + row) * 2;
                os[0] = cm.x; os[1] = 1.0f;
                float* ol = out + (size_t)BATCH * OUT_NUM * 7 +
                            ((size_t)b * OUT_NUM + row) * 3;
                ol[0] = cm.y; ol[1] = cm.z; ol[2] = 1.0f;
            }
        }
        __syncthreads();
    }

    for (int r = n_acc + t; r < OUT_NUM; r += 512) {
        float* ob = out + ((size_t)b * OUT_NUM + r) * 5;
        ob[0] = 0.f; ob[1] = 0.f; ob[2] = 0.f; ob[3] = 0.f; ob[4] = 0.f;
        float* os = out + (size_t)BATCH * OUT_NUM * 5 + ((size_t)b * OUT_NUM + r) * 2;
        os[0] = 0.f; os[1] = 0.f;
        float* ol = out + (size_t)BATCH * OUT_NUM * 7 + ((size_t)b * OUT_NUM + r) * 3;
        ol[0] = 0.f; ol[1] = 0.f; ol[2] = 0.f;
    }
    if (t == 0 && n_acc < OUT_NUM) out[0] = 2.0e5f;  // canary B
}

__global__ void canary_kernel(const uint32_t* __restrict__ flag, float* __restrict__ out,
                              int code) {
    if (code) { out[0] = 3.0e5f; return; }
    if (*flag) out[0] = 1.0e5f;
}

extern "C" void kernel_launch(void* const* d_in, const int* in_sizes, int n_in,
                              void* d_out, int out_size, void* d_ws, size_t ws_size,
                              hipStream_t stream) {
    const float* deltas  = (const float*)d_in[0];
    const float* logits  = (const float*)d_in[1];
    const float* anchors = (const float*)d_in[2];
    float* out = (float*)d_out;

    const size_t keysB = (size_t)BATCH * NELEM * 8;
    const size_t flagOff = keysB;
    const size_t stateOff = keysB + 256;
    const size_t kpreOff = keysB + 512;                       // 4 KB (PREWIN=16384)
    const size_t accOff = kpreOff + 8192;
    const size_t recOff = accOff + 65536;
    if (ws_size < recOff) {
        canary_kernel<<<1, 1, 0, stream>>>((const uint32_t*)d_ws, out, 1);
        return;
    }
    // tier select; walk block size encodes the tier for rocprof telemetry
    int M = 0, wbs = 512;
    const int tiers[3] = {8192, 4096, 2048};
    const int twbs[3]  = {512, 576, 640};
    for (int i = 0; i < 3; ++i) {
        int cand = tiers[i];
        size_t need = recOff + (size_t)BATCH * cand * 32 +
                      (size_t)BATCH * cand * (cand / 8) +
                      (size_t)BATCH * cand * 4 +
                      (size_t)BATCH * cand * KCAP * 2;
        if (ws_size >= need) { M = cand; wbs = twbs[i]; break; }
    }

    uint64_t* keys = (uint64_t*)d_ws;
    uint32_t* flag = (uint32_t*)((char*)d_ws + flagOff);
    uint32_t* state = (uint32_t*)((char*)d_ws + stateOff);
    uint64_t* kpre = (uint64_t*)((char*)d_ws + kpreOff);
    float4* accbox = (float4*)((char*)d_ws + accOff);
    float* records = (float*)((char*)d_ws + recOff);
    uint64_t* masks = (uint64_t*)((char*)d_ws + recOff + (size_t)BATCH * M * 32);
    uint32_t* kcount = (uint32_t*)((char*)masks + (size_t)BATCH * M * (M / 8));
    uint16_t* klist = (uint16_t*)((char*)kcount + (size_t)BATCH * M * 4);

    prep_kernel<<<(BATCH * NELEM) / 256, 256, 0, stream>>>(logits, keys, flag, state);

    bitonic_local_sort4<<<BATCH * NELEM / 4096, 1024, 0, stream>>>(keys);
    bitonic_local_merge8<<<BATCH * NELEM / 8192, 1024, 0, stream>>>(keys, 8192);
    bitonic_global_pass<<<(BATCH * NELEM / 2) / 256, 256, 0, stream>>>(keys, 16384, 8192);
    bitonic_local_merge8<<<BATCH * NELEM / 8192, 1024, 0, stream>>>(keys, 16384);
    bitonic_global_fused2<<<(BATCH * NELEM / 4) / 256, 256, 0, stream>>>(keys, 32768, 16384);
    bitonic_local_merge8<<<BATCH * NELEM / 8192, 1024, 0, stream>>>(keys, 32768);
    bitonic_global_fused3<<<(BATCH * NELEM / 8) / 256, 256, 0, stream>>>(keys, 65536, 32768);
    bitonic_local_merge8<<<BATCH * NELEM / 8192, 1024, 0, stream>>>(keys, 65536);
    bitonic_global_fused4<<<(BATCH * NELEM / 16) / 256, 256, 0, stream>>>(keys, 131072, 65536);
    bitonic_local_merge8<<<BATCH * NELEM / 8192, 1024, 0, stream>>>(keys, 131072);

    sort_check<<<(BATCH * NELEM) / 256, 256, 0, stream>>>(keys, flag);
    if (M > 0) {
        records_kernel<<<(BATCH * M) / 256, 256, 0, stream>>>(keys, deltas, anchors,
                                                              logits, records, kcount, M);
        dim3 mg(M / 64, M / 64, BATCH);
        mask_kernel<<<mg, 64, 0, stream>>>(records, masks, kcount, klist, M);
        nms_walk<<<BATCH, wbs, 0, stream>>>(records, masks, kcount, klist,
                                            accbox, state, out, M);
        accsort_kernel<<<BATCH, 1024, 0, stream>>>(accbox, state, flag);
        dim3 pg(PREWIN / 64, BATCH);
        prekill_kernel<<<pg, 1024, 0, stream>>>(keys, deltas, anchors, accbox, state,
                                                kpre, M);
    }
    nms_tail<<<BATCH, 512, 0, stream>>>(keys, deltas, logits, anchors, accbox, state,
                                        kpre, out, M, (M > 0) ? 1 : 0);
    canary_kernel<<<1, 1, 0, stream>>>(flag, out, 0);
}